// Round 1
// baseline (407.422 us; speedup 1.0000x reference)
//
#include <hip/hip_runtime.h>
#include <hip/hip_bf16.h>
#include <float.h>

#define B_ 8
#define N_ 8192
#define M_ 2048
#define CC_ 256
#define CP_ 128
#define CIN_ 384
#define GRP_ 8

typedef __attribute__((ext_vector_type(8))) short short8;
typedef __attribute__((ext_vector_type(4))) short short4v;
typedef __attribute__((ext_vector_type(4))) float f32x4;

static __device__ __forceinline__ float bf2f(unsigned short u) {
  union { unsigned int i; float f; } v; v.i = ((unsigned int)u) << 16; return v.f;
}
static __device__ __forceinline__ unsigned short f2bf(float f) {
  union { float f; unsigned int i; } v; v.f = f;
  unsigned int u = v.i;
  unsigned int r = (u + 0x7FFFu + ((u >> 16) & 1u)) >> 16;
  return (unsigned short)r;
}

// ---------------- weight cast ----------------
__global__ void k_wcast(const float* __restrict__ W1, const float* __restrict__ W2,
                        short* __restrict__ W1b, short* __restrict__ W2b) {
  int i = blockIdx.x * blockDim.x + threadIdx.x;
  if (i < 256 * CIN_) W1b[i] = (short)f2bf(W1[i]);
  if (i < 256 * 256)  W2b[i] = (short)f2bf(W2[i]);
}

// ---------------- transpose + cast: [b][C][Nn] f32 -> [b][Nn][RS] bf16 at col off ----
__global__ __launch_bounds__(256) void k_transpose_cast(
    const float* __restrict__ in, short* __restrict__ out,
    int C, int Nn, int RS, int coff) {
  __shared__ float tile[32][33];
  int b = blockIdx.z;
  const float* inb = in + (size_t)b * C * Nn;
  short* outb = out + (size_t)b * Nn * RS;
  int n0 = blockIdx.x * 32, c0 = blockIdx.y * 32;
  int tx = threadIdx.x & 31, ty = threadIdx.x >> 5;
#pragma unroll
  for (int i = 0; i < 32; i += 8)
    tile[ty + i][tx] = inb[(size_t)(c0 + ty + i) * Nn + n0 + tx];
  __syncthreads();
#pragma unroll
  for (int i = 0; i < 32; i += 8)
    outb[(size_t)(n0 + ty + i) * RS + coff + c0 + tx] = (short)f2bf(tile[tx][ty + i]);
}

// ---------------- 3-NN ----------------
__global__ __launch_bounds__(256) void k_knn(
    const float* __restrict__ pc, const float* __restrict__ cc,
    int* __restrict__ idx, float* __restrict__ wts) {
  __shared__ float cx[M_], cy[M_], cz[M_];
  int b = blockIdx.y;
  int t = threadIdx.x;
  const float* ccb = cc + (size_t)b * 3 * M_;
  for (int i = t; i < M_; i += 256) {
    cx[i] = ccb[i]; cy[i] = ccb[M_ + i]; cz[i] = ccb[2 * M_ + i];
  }
  __syncthreads();
  int n = blockIdx.x * 256 + t;
  const float* pcb = pc + (size_t)b * 3 * N_;
  float px = pcb[n], py = pcb[N_ + n], pz = pcb[2 * N_ + n];
  float d0 = FLT_MAX, d1 = FLT_MAX, d2 = FLT_MAX;
  int i0 = 0, i1 = 0, i2 = 0;
  for (int m = 0; m < M_; ++m) {
    float dx = px - cx[m], dy = py - cy[m], dz = pz - cz[m];
    float d = dx * dx + dy * dy + dz * dz;
    bool c0 = d < d0, c1 = d < d1, c2 = d < d2;
    float nb2 = c1 ? d1 : (c2 ? d : d2);
    int   ni2 = c1 ? i1 : (c2 ? m : i2);
    float nb1 = c0 ? d0 : (c1 ? d : d1);
    int   ni1 = c0 ? i0 : (c1 ? m : i1);
    d0 = c0 ? d : d0; i0 = c0 ? m : i0;
    d1 = nb1; i1 = ni1; d2 = nb2; i2 = ni2;
  }
  float w0 = 1.f / (d0 + 1e-8f), w1 = 1.f / (d1 + 1e-8f), w2 = 1.f / (d2 + 1e-8f);
  float inv = 1.f / (w0 + w1 + w2);
  int bn = b * N_ + n;
  wts[bn] = w0 * inv; wts[B_ * N_ + bn] = w1 * inv; wts[2 * B_ * N_ + bn] = w2 * inv;
  idx[bn] = i0; idx[B_ * N_ + bn] = i1; idx[2 * B_ * N_ + bn] = i2;
}

// ---------------- gather + weighted sum -> x0T[b][n][0..256) ----------------
__global__ __launch_bounds__(256) void k_interp(
    const short* __restrict__ FT, const int* __restrict__ idx,
    const float* __restrict__ wts, short* __restrict__ x0T) {
  int b = blockIdx.y;
  int t = threadIdx.x;
  int nl = t >> 5, cch = (t & 31) * 8;
  int n = blockIdx.x * 8 + nl;
  int bn = b * N_ + n;
  int i0 = idx[bn], i1 = idx[B_ * N_ + bn], i2 = idx[2 * B_ * N_ + bn];
  float w0 = wts[bn], w1 = wts[B_ * N_ + bn], w2 = wts[2 * B_ * N_ + bn];
  const short* Fb = FT + (size_t)b * M_ * CC_;
  short8 f0 = *(const short8*)(Fb + (size_t)i0 * CC_ + cch);
  short8 f1 = *(const short8*)(Fb + (size_t)i1 * CC_ + cch);
  short8 f2 = *(const short8*)(Fb + (size_t)i2 * CC_ + cch);
  short8 r;
#pragma unroll
  for (int e = 0; e < 8; ++e) {
    float v = w0 * bf2f((unsigned short)f0[e]) + w1 * bf2f((unsigned short)f1[e]) +
              w2 * bf2f((unsigned short)f2[e]);
    r[e] = (short)f2bf(v);
  }
  *(short8*)(x0T + (size_t)bn * CIN_ + cch) = r;
}

// ---------------- bf16 MFMA GEMM: Y[b][n][o] = W[o][:] . X[b][n][:] + bias ----------------
__global__ __launch_bounds__(256) void k_gemm(
    const short* __restrict__ Wb, const short* __restrict__ Xb,
    const float* __restrict__ bias, short* __restrict__ Yb, int K) {
  __shared__ __align__(16) short sW[64 * 32];
  __shared__ __align__(16) short sX[64 * 32];
  int b = blockIdx.z;
  int otile = blockIdx.x * 64;
  int ntile = blockIdx.y * 64;
  int t = threadIdx.x;
  int wave = t >> 6, lane = t & 63;
  f32x4 acc0 = {0.f, 0.f, 0.f, 0.f}, acc1 = acc0, acc2 = acc0, acc3 = acc0;
  const short* Wp = Wb + (size_t)otile * K;
  const short* Xp = Xb + ((size_t)b * N_ + ntile) * K;
  int srow = t >> 2;
  int scol = (t & 3) * 8;
  int frow = lane & 15;
  int fk = (lane >> 4) * 8;
  for (int k0 = 0; k0 < K; k0 += 32) {
    short8 w8 = *(const short8*)(Wp + (size_t)srow * K + k0 + scol);
    short8 x8 = *(const short8*)(Xp + (size_t)srow * K + k0 + scol);
    __syncthreads();
    *(short8*)(sW + srow * 32 + scol) = w8;
    *(short8*)(sX + srow * 32 + scol) = x8;
    __syncthreads();
    short8 a   = *(const short8*)(sW + (wave * 16 + frow) * 32 + fk);
    short8 bq0 = *(const short8*)(sX + (0 * 16 + frow) * 32 + fk);
    short8 bq1 = *(const short8*)(sX + (1 * 16 + frow) * 32 + fk);
    short8 bq2 = *(const short8*)(sX + (2 * 16 + frow) * 32 + fk);
    short8 bq3 = *(const short8*)(sX + (3 * 16 + frow) * 32 + fk);
    acc0 = __builtin_amdgcn_mfma_f32_16x16x32_bf16(a, bq0, acc0, 0, 0, 0);
    acc1 = __builtin_amdgcn_mfma_f32_16x16x32_bf16(a, bq1, acc1, 0, 0, 0);
    acc2 = __builtin_amdgcn_mfma_f32_16x16x32_bf16(a, bq2, acc2, 0, 0, 0);
    acc3 = __builtin_amdgcn_mfma_f32_16x16x32_bf16(a, bq3, acc3, 0, 0, 0);
  }
  int olocal = wave * 16 + (lane >> 4) * 4;
  int o = otile + olocal;
  float bi0 = bias[o], bi1 = bias[o + 1], bi2 = bias[o + 2], bi3 = bias[o + 3];
  int nloc = lane & 15;
#define STORE_TILE(J, ACC) { \
    int n = ntile + (J) * 16 + nloc; \
    short4v sv; \
    sv[0] = (short)f2bf(ACC[0] + bi0); \
    sv[1] = (short)f2bf(ACC[1] + bi1); \
    sv[2] = (short)f2bf(ACC[2] + bi2); \
    sv[3] = (short)f2bf(ACC[3] + bi3); \
    *(short4v*)(Yb + ((size_t)b * N_ + n) * 256 + o) = sv; }
  STORE_TILE(0, acc0)
  STORE_TILE(1, acc1)
  STORE_TILE(2, acc2)
  STORE_TILE(3, acc3)
#undef STORE_TILE
}

// ---------------- GroupNorm stats (partials) ----------------
__global__ __launch_bounds__(256) void k_gnstats(const short* __restrict__ Y,
                                                 float* __restrict__ part) {
  int b = blockIdx.y, sp = blockIdx.x;
  int t = threadIdx.x;
  int o2 = t & 127, nh = t >> 7;
  const unsigned int* Yd = (const unsigned int*)(Y + (size_t)b * N_ * 256);
  float s = 0.f, ss = 0.f;
  int nend = (sp + 1) * 512;
  for (int n = sp * 512 + nh; n < nend; n += 2) {
    unsigned int v = Yd[(size_t)n * 128 + o2];
    float a = bf2f((unsigned short)(v & 0xFFFF));
    float c = bf2f((unsigned short)(v >> 16));
    s += a + c; ss += a * a + c * c;
  }
  __shared__ float S[256], SS[256];
  S[t] = s; SS[t] = ss;
  __syncthreads();
  if (t < 8) {
    float a = 0.f, c = 0.f;
    for (int j = 0; j < 16; ++j) {
      a += S[t * 16 + j] + S[128 + t * 16 + j];
      c += SS[t * 16 + j] + SS[128 + t * 16 + j];
    }
    part[(((size_t)b * 8 + t) * 16 + sp) * 2] = a;
    part[(((size_t)b * 8 + t) * 16 + sp) * 2 + 1] = c;
  }
}

__global__ void k_gnfinal(const float* __restrict__ part, float* __restrict__ fin) {
  int t = threadIdx.x;  // 64 = B*G
  float s = 0.f, ss = 0.f;
  for (int j = 0; j < 16; ++j) {
    s += part[((size_t)t * 16 + j) * 2];
    ss += part[((size_t)t * 16 + j) * 2 + 1];
  }
  const float cnt = 32.f * 8192.f;
  float mean = s / cnt;
  float var = ss / cnt - mean * mean;
  fin[t * 2] = mean;
  fin[t * 2 + 1] = rsqrtf(var + 1e-5f);
}

// ---------------- GN + swish in place (bf16 [b][n][256]) ----------------
__global__ __launch_bounds__(256) void k_gnapply(short* __restrict__ Y,
                                                 const float* __restrict__ fin,
                                                 const float* __restrict__ gw,
                                                 const float* __restrict__ gb) {
  unsigned int* Yd = (unsigned int*)Y;
  int total = B_ * N_ * 128;
  for (int i = blockIdx.x * blockDim.x + threadIdx.x; i < total;
       i += gridDim.x * blockDim.x) {
    int o2 = i & 127;
    int b = i >> 20;
    int g = o2 >> 4;
    float mean = fin[(b * 8 + g) * 2], rstd = fin[(b * 8 + g) * 2 + 1];
    unsigned int v = Yd[i];
    int o = o2 * 2;
    float a = bf2f((unsigned short)(v & 0xFFFF));
    float c = bf2f((unsigned short)(v >> 16));
    a = (a - mean) * rstd * gw[o] + gb[o];
    c = (c - mean) * rstd * gw[o + 1] + gb[o + 1];
    a = a / (1.f + __expf(-a));
    c = c / (1.f + __expf(-c));
    Yd[i] = (unsigned int)f2bf(a) | ((unsigned int)f2bf(c) << 16);
  }
}

// ---------------- GN + swish + transpose -> out [b][o][n] f32 ----------------
__global__ __launch_bounds__(256) void k_gnapply_out(
    const short* __restrict__ Y, const float* __restrict__ fin,
    const float* __restrict__ gw, const float* __restrict__ gb,
    float* __restrict__ out) {
  __shared__ float tile[64][65];
  int b = blockIdx.z;
  int n0 = blockIdx.x * 64, o0 = blockIdx.y * 64;
  int t = threadIdx.x;
  int row = t >> 5, dcol = t & 31;
  const unsigned int* Yd = (const unsigned int*)(Y + (size_t)b * N_ * 256);
  int o = o0 + dcol * 2;
  int g = o >> 5;
  float mean = fin[(b * 8 + g) * 2], rstd = fin[(b * 8 + g) * 2 + 1];
  float w0 = gw[o], w1 = gw[o + 1], bb0 = gb[o], bb1 = gb[o + 1];
#pragma unroll
  for (int p = 0; p < 8; ++p) {
    int n = n0 + p * 8 + row;
    unsigned int v = Yd[(size_t)n * 128 + (o0 >> 1) + dcol];
    float a = bf2f((unsigned short)(v & 0xFFFF));
    float c = bf2f((unsigned short)(v >> 16));
    a = (a - mean) * rstd * w0 + bb0; a = a / (1.f + __expf(-a));
    c = (c - mean) * rstd * w1 + bb1; c = c / (1.f + __expf(-c));
    tile[p * 8 + row][dcol * 2] = a;
    tile[p * 8 + row][dcol * 2 + 1] = c;
  }
  __syncthreads();
  int ol = t >> 2, nch = (t & 3) * 16;
  float* ob = out + ((size_t)(b * 256 + o0 + ol)) * N_ + n0 + nch;
#pragma unroll
  for (int c4 = 0; c4 < 16; c4 += 4) {
    float4 v4;
    v4.x = tile[nch + c4 + 0][ol];
    v4.y = tile[nch + c4 + 1][ol];
    v4.z = tile[nch + c4 + 2][ol];
    v4.w = tile[nch + c4 + 3][ol];
    *(float4*)(ob + c4) = v4;
  }
}

// ---------------- tail: coords copy + time_emb broadcast ----------------
__global__ void k_tail(const float* __restrict__ pc, const float* __restrict__ te,
                       float* __restrict__ out) {
  int total = 196608 + B_ * 64 * N_;
  for (int i = blockIdx.x * blockDim.x + threadIdx.x; i < total;
       i += gridDim.x * blockDim.x) {
    if (i < 196608) {
      out[16777216 + i] = pc[i];
    } else {
      int j = i - 196608;
      int bd = j >> 13;
      out[16973824 + j] = te[bd];
    }
  }
}

extern "C" void kernel_launch(void* const* d_in, const int* in_sizes, int n_in,
                              void* d_out, int out_size, void* d_ws, size_t ws_size,
                              hipStream_t stream) {
  const float* pc  = (const float*)d_in[0];
  const float* cc  = (const float*)d_in[1];
  const float* cf  = (const float*)d_in[2];
  const float* pf  = (const float*)d_in[3];
  const float* te  = (const float*)d_in[4];
  const float* W1  = (const float*)d_in[5];
  const float* b1  = (const float*)d_in[6];
  const float* g1w = (const float*)d_in[7];
  const float* g1b = (const float*)d_in[8];
  const float* W2  = (const float*)d_in[9];
  const float* b2  = (const float*)d_in[10];
  const float* g2w = (const float*)d_in[11];
  const float* g2b = (const float*)d_in[12];
  float* out = (float*)d_out;

  char* ws = (char*)d_ws;
  size_t off = 0;
  auto alloc = [&](size_t bytes) {
    char* p = ws + off;
    off += (bytes + 255) & ~(size_t)255;
    return p;
  };
  short* FT   = (short*)alloc((size_t)B_ * M_ * CC_ * 2);       // 8.4 MB
  short* x0T  = (short*)alloc((size_t)B_ * N_ * CIN_ * 2);      // 50.3 MB
  short* y1   = (short*)alloc((size_t)B_ * N_ * 256 * 2);       // 33.6 MB
  short* W1b  = (short*)alloc(256 * 384 * 2);
  short* W2b  = (short*)alloc(256 * 256 * 2);
  int*   idx  = (int*)alloc((size_t)3 * B_ * N_ * 4);
  float* wts  = (float*)alloc((size_t)3 * B_ * N_ * 4);
  float* part = (float*)alloc(8 * 8 * 16 * 2 * 4);
  float* fin1 = (float*)alloc(64 * 2 * 4);
  float* fin2 = (float*)alloc(64 * 2 * 4);
  short* y2 = (short*)x0T;  // x0T dead after gemm1; reuse for y2

  k_wcast<<<384, 256, 0, stream>>>(W1, W2, W1b, W2b);
  k_transpose_cast<<<dim3(M_ / 32, CC_ / 32, B_), 256, 0, stream>>>(cf, FT, CC_, M_, CC_, 0);
  k_transpose_cast<<<dim3(N_ / 32, CP_ / 32, B_), 256, 0, stream>>>(pf, x0T, CP_, N_, CIN_, 256);
  k_knn<<<dim3(N_ / 256, B_), 256, 0, stream>>>(pc, cc, idx, wts);
  k_interp<<<dim3(N_ / 8, B_), 256, 0, stream>>>(FT, idx, wts, x0T);
  k_gemm<<<dim3(4, N_ / 64, B_), 256, 0, stream>>>(W1b, x0T, b1, y1, CIN_);
  k_gnstats<<<dim3(16, B_), 256, 0, stream>>>(y1, part);
  k_gnfinal<<<1, 64, 0, stream>>>(part, fin1);
  k_gnapply<<<2048, 256, 0, stream>>>(y1, fin1, g1w, g1b);
  k_gemm<<<dim3(4, N_ / 64, B_), 256, 0, stream>>>(W2b, y1, b2, y2, 256);
  k_gnstats<<<dim3(16, B_), 256, 0, stream>>>(y2, part);
  k_gnfinal<<<1, 64, 0, stream>>>(part, fin2);
  k_gnapply_out<<<dim3(N_ / 64, 4, B_), 256, 0, stream>>>(y2, fin2, g2w, g2b, out);
  k_tail<<<2048, 256, 0, stream>>>(pc, te, out);
}

// Round 3
// 346.746 us; speedup vs baseline: 1.1750x; 1.1750x over previous
//
#include <hip/hip_runtime.h>
#include <hip/hip_bf16.h>
#include <float.h>

#define B_ 8
#define N_ 8192
#define M_ 2048
#define CC_ 256
#define CP_ 128
#define CIN_ 384
#define GRP_ 8

typedef __attribute__((ext_vector_type(8))) short short8;
typedef __attribute__((ext_vector_type(4))) short short4v;
typedef __attribute__((ext_vector_type(4))) float f32x4;

static __device__ __forceinline__ float bf2f(unsigned short u) {
  union { unsigned int i; float f; } v; v.i = ((unsigned int)u) << 16; return v.f;
}
static __device__ __forceinline__ unsigned short f2bf(float f) {
  union { float f; unsigned int i; } v; v.f = f;
  unsigned int u = v.i;
  unsigned int r = (u + 0x7FFFu + ((u >> 16) & 1u)) >> 16;
  return (unsigned short)r;
}
static __device__ __forceinline__ void gload16(const void* g, void* l) {
  __builtin_amdgcn_global_load_lds(
      (const __attribute__((address_space(1))) void*)g,
      (__attribute__((address_space(3))) void*)l, 16, 0, 0);
}

// ---------------- weight cast ----------------
__global__ void k_wcast(const float* __restrict__ W1, const float* __restrict__ W2,
                        short* __restrict__ W1b, short* __restrict__ W2b) {
  int i = blockIdx.x * blockDim.x + threadIdx.x;
  if (i < 256 * CIN_) W1b[i] = (short)f2bf(W1[i]);
  if (i < 256 * 256)  W2b[i] = (short)f2bf(W2[i]);
}

// ---------------- transpose + cast: [b][C][Nn] f32 -> [b][Nn][RS] bf16 at col off ----
__global__ __launch_bounds__(256) void k_transpose_cast(
    const float* __restrict__ in, short* __restrict__ out,
    int C, int Nn, int RS, int coff) {
  __shared__ float tile[32][33];
  int b = blockIdx.z;
  const float* inb = in + (size_t)b * C * Nn;
  short* outb = out + (size_t)b * Nn * RS;
  int n0 = blockIdx.x * 32, c0 = blockIdx.y * 32;
  int tx = threadIdx.x & 31, ty = threadIdx.x >> 5;
#pragma unroll
  for (int i = 0; i < 32; i += 8)
    tile[ty + i][tx] = inb[(size_t)(c0 + ty + i) * Nn + n0 + tx];
  __syncthreads();
#pragma unroll
  for (int i = 0; i < 32; i += 8)
    outb[(size_t)(n0 + ty + i) * RS + coff + c0 + tx] = (short)f2bf(tile[tx][ty + i]);
}

// ---------------- 3-NN: 4-way M-chunked, branchless top-3, EXACT fp32 distances ----
__global__ __launch_bounds__(256) void k_knn(
    const float* __restrict__ pc, const float* __restrict__ cc,
    int* __restrict__ idx, float* __restrict__ wts) {
  __shared__ __align__(16) float4 ctr[M_];     // 32 KB
  __shared__ float md[4][3][64];
  __shared__ int   mi[4][3][64];
  int b = blockIdx.y;
  int t = threadIdx.x;
  const float* ccb = cc + (size_t)b * 3 * M_;
  for (int i = t; i < M_; i += 256) {
    float x = ccb[i], y = ccb[M_ + i], z = ccb[2 * M_ + i];
    ctr[i] = make_float4(x, y, z, x * x + y * y + z * z);
  }
  __syncthreads();
  int wv = t >> 6, lane = t & 63;
  int n = blockIdx.x * 64 + lane;
  const float* pcb = pc + (size_t)b * 3 * N_;
  float px = pcb[n], py = pcb[N_ + n], pz = pcb[2 * N_ + n];
  float p2 = px * px + py * py + pz * pz;
  float d0 = FLT_MAX, d1 = FLT_MAX, d2 = FLT_MAX;
  int i0 = 0, i1 = 0, i2 = 0;
  const float4* C = ctr + wv * 512;
  int mbase = wv * 512;
#pragma unroll 8
  for (int m = 0; m < 512; ++m) {
    float4 c = C[m];                           // wave-uniform -> LDS broadcast
    float dot = px * c.x;
    dot = __builtin_fmaf(py, c.y, dot);
    dot = __builtin_fmaf(pz, c.z, dot);
    float d = __builtin_fmaf(-2.f, dot, c.w) + p2;
    int im = mbase + m;
    bool c0 = d < d0, c1 = d < d1, c2 = d < d2;
    i2 = c2 ? (c1 ? i1 : im) : i2;             // uses OLD i1
    i1 = c1 ? (c0 ? i0 : im) : i1;             // uses OLD i0
    i0 = c0 ? im : i0;
    d2 = fminf(fmaxf(d, d1), d2);              // uses OLD d1
    d1 = __builtin_amdgcn_fmed3f(d, d0, d1);   // uses OLD d0
    d0 = fminf(d, d0);
  }
  md[wv][0][lane] = d0; mi[wv][0][lane] = i0;
  md[wv][1][lane] = d1; mi[wv][1][lane] = i1;
  md[wv][2][lane] = d2; mi[wv][2][lane] = i2;
  __syncthreads();
  if (t < 64) {
#pragma unroll
    for (int w = 1; w < 4; ++w) {
#pragma unroll
      for (int j = 0; j < 3; ++j) {
        float d = md[w][j][t]; int im = mi[w][j][t];
        bool c0 = d < d0, c1 = d < d1, c2 = d < d2;
        i2 = c2 ? (c1 ? i1 : im) : i2;
        i1 = c1 ? (c0 ? i0 : im) : i1;
        i0 = c0 ? im : i0;
        d2 = fminf(fmaxf(d, d1), d2);
        d1 = __builtin_amdgcn_fmed3f(d, d0, d1);
        d0 = fminf(d, d0);
      }
    }
    float w0 = 1.f / (d0 + 1e-8f), w1 = 1.f / (d1 + 1e-8f), w2 = 1.f / (d2 + 1e-8f);
    float inv = 1.f / (w0 + w1 + w2);
    int bn = b * N_ + blockIdx.x * 64 + t;
    wts[bn] = w0 * inv; wts[B_ * N_ + bn] = w1 * inv; wts[2 * B_ * N_ + bn] = w2 * inv;
    idx[bn] = i0;
    idx[B_ * N_ + bn] = i1;
    idx[2 * B_ * N_ + bn] = i2;
  }
}

// ---------------- gather + weighted sum -> x0T[b][n][0..256) ----------------
__global__ __launch_bounds__(256) void k_interp(
    const short* __restrict__ FT, const int* __restrict__ idx,
    const float* __restrict__ wts, short* __restrict__ x0T) {
  int b = blockIdx.y;
  int t = threadIdx.x;
  int nl = t >> 5, cch = (t & 31) * 8;
  int n = blockIdx.x * 8 + nl;
  int bn = b * N_ + n;
  int i0 = idx[bn], i1 = idx[B_ * N_ + bn], i2 = idx[2 * B_ * N_ + bn];
  float w0 = wts[bn], w1 = wts[B_ * N_ + bn], w2 = wts[2 * B_ * N_ + bn];
  const short* Fb = FT + (size_t)b * M_ * CC_;
  short8 f0 = *(const short8*)(Fb + (size_t)i0 * CC_ + cch);
  short8 f1 = *(const short8*)(Fb + (size_t)i1 * CC_ + cch);
  short8 f2 = *(const short8*)(Fb + (size_t)i2 * CC_ + cch);
  short8 r;
#pragma unroll
  for (int e = 0; e < 8; ++e) {
    float v = w0 * bf2f((unsigned short)f0[e]) + w1 * bf2f((unsigned short)f1[e]) +
              w2 * bf2f((unsigned short)f2[e]);
    r[e] = (short)f2bf(v);
  }
  *(short8*)(x0T + (size_t)bn * CIN_ + cch) = r;
}

// ---------------- bf16 MFMA GEMM (m97-style): 128x128 tile, BK=64, gload_lds, XOR swizzle ----
// Y[b][n][o] = W[o][:] . X[b][n][:] + bias[o], all operands row-major with k contiguous.
__global__ __launch_bounds__(256) void k_gemm(
    const short* __restrict__ Wb, const short* __restrict__ Xb,
    const float* __restrict__ bias, short* __restrict__ Yb, int K) {
  __shared__ __align__(16) short sW[128 * 64];   // 16 KB
  __shared__ __align__(16) short sX[128 * 64];   // 16 KB
  int b = blockIdx.z;
  int otile = blockIdx.x * 128;
  int ntile = blockIdx.y * 128;
  int t = threadIdx.x;
  int wv = t >> 6, lane = t & 63;
  int wr = wv >> 1, wc = wv & 1;
  int fr = lane & 15;     // fragment row
  int g = lane >> 4;      // k-subchunk selector
  f32x4 acc[4][4] = {};
  const short* Wp = Wb + (size_t)otile * K;
  const short* Xp = Xb + ((size_t)b * N_ + ntile) * K;
  for (int k0 = 0; k0 < K; k0 += 64) {
#pragma unroll
    for (int j = 0; j < 4; ++j) {
      int s = j * 256 + t;          // slot 0..1023, 16B each
      int row = s >> 3;             // 8 slots (128B) per row
      int kc = (s & 7) ^ (row & 7); // inverse-swizzled source chunk
      gload16(Wp + (size_t)row * K + k0 + kc * 8, sW + j * 2048 + wv * 512);
      gload16(Xp + (size_t)row * K + k0 + kc * 8, sX + j * 2048 + wv * 512);
    }
    __syncthreads();
#pragma unroll
    for (int h = 0; h < 2; ++h) {
      short8 af[4], bfr[4];
#pragma unroll
      for (int m = 0; m < 4; ++m) {
        int ra = wr * 64 + m * 16 + fr;
        af[m] = *(const short8*)(sW + ra * 64 + (((h * 4 + g) ^ (ra & 7)) << 3));
        int rb = wc * 64 + m * 16 + fr;
        bfr[m] = *(const short8*)(sX + rb * 64 + (((h * 4 + g) ^ (rb & 7)) << 3));
      }
#pragma unroll
      for (int m = 0; m < 4; ++m)
#pragma unroll
        for (int nn = 0; nn < 4; ++nn)
          acc[m][nn] = __builtin_amdgcn_mfma_f32_16x16x32_bf16(af[m], bfr[nn], acc[m][nn], 0, 0, 0);
    }
    __syncthreads();
  }
#pragma unroll
  for (int m = 0; m < 4; ++m) {
    int o = otile + wr * 64 + m * 16 + g * 4;
    float4 bi = *(const float4*)(bias + o);
#pragma unroll
    for (int nn = 0; nn < 4; ++nn) {
      int n = ntile + wc * 64 + nn * 16 + fr;
      short4v sv;
      sv[0] = (short)f2bf(acc[m][nn][0] + bi.x);
      sv[1] = (short)f2bf(acc[m][nn][1] + bi.y);
      sv[2] = (short)f2bf(acc[m][nn][2] + bi.z);
      sv[3] = (short)f2bf(acc[m][nn][3] + bi.w);
      *(short4v*)(Yb + ((size_t)b * N_ + n) * 256 + o) = sv;
    }
  }
}

// ---------------- GroupNorm stats (partials) ----------------
__global__ __launch_bounds__(256) void k_gnstats(const short* __restrict__ Y,
                                                 float* __restrict__ part) {
  int b = blockIdx.y, sp = blockIdx.x;
  int t = threadIdx.x;
  int o2 = t & 127, nh = t >> 7;
  const unsigned int* Yd = (const unsigned int*)(Y + (size_t)b * N_ * 256);
  float s = 0.f, ss = 0.f;
  int nend = (sp + 1) * 512;
  for (int n = sp * 512 + nh; n < nend; n += 2) {
    unsigned int v = Yd[(size_t)n * 128 + o2];
    float a = bf2f((unsigned short)(v & 0xFFFF));
    float c = bf2f((unsigned short)(v >> 16));
    s += a + c; ss += a * a + c * c;
  }
  __shared__ float S[256], SS[256];
  S[t] = s; SS[t] = ss;
  __syncthreads();
  if (t < 8) {
    float a = 0.f, c = 0.f;
    for (int j = 0; j < 16; ++j) {
      a += S[t * 16 + j] + S[128 + t * 16 + j];
      c += SS[t * 16 + j] + SS[128 + t * 16 + j];
    }
    part[(((size_t)b * 8 + t) * 16 + sp) * 2] = a;
    part[(((size_t)b * 8 + t) * 16 + sp) * 2 + 1] = c;
  }
}

__global__ void k_gnfinal(const float* __restrict__ part, float* __restrict__ fin) {
  int t = threadIdx.x;  // 64 = B*G
  float s = 0.f, ss = 0.f;
  for (int j = 0; j < 16; ++j) {
    s += part[((size_t)t * 16 + j) * 2];
    ss += part[((size_t)t * 16 + j) * 2 + 1];
  }
  const float cnt = 32.f * 8192.f;
  float mean = s / cnt;
  float var = ss / cnt - mean * mean;
  fin[t * 2] = mean;
  fin[t * 2 + 1] = rsqrtf(var + 1e-5f);
}

// ---------------- GN + swish in place (bf16 [b][n][256]) ----------------
__global__ __launch_bounds__(256) void k_gnapply(short* __restrict__ Y,
                                                 const float* __restrict__ fin,
                                                 const float* __restrict__ gw,
                                                 const float* __restrict__ gb) {
  unsigned int* Yd = (unsigned int*)Y;
  int total = B_ * N_ * 128;
  for (int i = blockIdx.x * blockDim.x + threadIdx.x; i < total;
       i += gridDim.x * blockDim.x) {
    int o2 = i & 127;
    int b = i >> 20;
    int g = o2 >> 4;
    float mean = fin[(b * 8 + g) * 2], rstd = fin[(b * 8 + g) * 2 + 1];
    unsigned int v = Yd[i];
    int o = o2 * 2;
    float a = bf2f((unsigned short)(v & 0xFFFF));
    float c = bf2f((unsigned short)(v >> 16));
    a = (a - mean) * rstd * gw[o] + gb[o];
    c = (c - mean) * rstd * gw[o + 1] + gb[o + 1];
    a = a / (1.f + __expf(-a));
    c = c / (1.f + __expf(-c));
    Yd[i] = (unsigned int)f2bf(a) | ((unsigned int)f2bf(c) << 16);
  }
}

// ---------------- GN + swish + transpose -> out [b][o][n] f32 ----------------
__global__ __launch_bounds__(256) void k_gnapply_out(
    const short* __restrict__ Y, const float* __restrict__ fin,
    const float* __restrict__ gw, const float* __restrict__ gb,
    float* __restrict__ out) {
  __shared__ float tile[64][65];
  int b = blockIdx.z;
  int n0 = blockIdx.x * 64, o0 = blockIdx.y * 64;
  int t = threadIdx.x;
  int row = t >> 5, dcol = t & 31;
  const unsigned int* Yd = (const unsigned int*)(Y + (size_t)b * N_ * 256);
  int o = o0 + dcol * 2;
  int g = o >> 5;
  float mean = fin[(b * 8 + g) * 2], rstd = fin[(b * 8 + g) * 2 + 1];
  float w0 = gw[o], w1 = gw[o + 1], bb0 = gb[o], bb1 = gb[o + 1];
#pragma unroll
  for (int p = 0; p < 8; ++p) {
    int n = n0 + p * 8 + row;
    unsigned int v = Yd[(size_t)n * 128 + (o0 >> 1) + dcol];
    float a = bf2f((unsigned short)(v & 0xFFFF));
    float c = bf2f((unsigned short)(v >> 16));
    a = (a - mean) * rstd * w0 + bb0; a = a / (1.f + __expf(-a));
    c = (c - mean) * rstd * w1 + bb1; c = c / (1.f + __expf(-c));
    tile[p * 8 + row][dcol * 2] = a;
    tile[p * 8 + row][dcol * 2 + 1] = c;
  }
  __syncthreads();
  int ol = t >> 2, nch = (t & 3) * 16;
  float* ob = out + ((size_t)(b * 256 + o0 + ol)) * N_ + n0 + nch;
#pragma unroll
  for (int c4 = 0; c4 < 16; c4 += 4) {
    float4 v4;
    v4.x = tile[nch + c4 + 0][ol];
    v4.y = tile[nch + c4 + 1][ol];
    v4.z = tile[nch + c4 + 2][ol];
    v4.w = tile[nch + c4 + 3][ol];
    *(float4*)(ob + c4) = v4;
  }
}

// ---------------- tail: coords copy + time_emb broadcast ----------------
__global__ void k_tail(const float* __restrict__ pc, const float* __restrict__ te,
                       float* __restrict__ out) {
  int total = 196608 + B_ * 64 * N_;
  for (int i = blockIdx.x * blockDim.x + threadIdx.x; i < total;
       i += gridDim.x * blockDim.x) {
    if (i < 196608) {
      out[16777216 + i] = pc[i];
    } else {
      int j = i - 196608;
      int bd = j >> 13;
      out[16973824 + j] = te[bd];
    }
  }
}

extern "C" void kernel_launch(void* const* d_in, const int* in_sizes, int n_in,
                              void* d_out, int out_size, void* d_ws, size_t ws_size,
                              hipStream_t stream) {
  const float* pc  = (const float*)d_in[0];
  const float* cc  = (const float*)d_in[1];
  const float* cf  = (const float*)d_in[2];
  const float* pf  = (const float*)d_in[3];
  const float* te  = (const float*)d_in[4];
  const float* W1  = (const float*)d_in[5];
  const float* b1  = (const float*)d_in[6];
  const float* g1w = (const float*)d_in[7];
  const float* g1b = (const float*)d_in[8];
  const float* W2  = (const float*)d_in[9];
  const float* b2  = (const float*)d_in[10];
  const float* g2w = (const float*)d_in[11];
  const float* g2b = (const float*)d_in[12];
  float* out = (float*)d_out;

  char* ws = (char*)d_ws;
  size_t off = 0;
  auto alloc = [&](size_t bytes) {
    char* p = ws + off;
    off += (bytes + 255) & ~(size_t)255;
    return p;
  };
  short* FT   = (short*)alloc((size_t)B_ * M_ * CC_ * 2);       // 8.4 MB
  short* x0T  = (short*)alloc((size_t)B_ * N_ * CIN_ * 2);      // 50.3 MB
  short* y1   = (short*)alloc((size_t)B_ * N_ * 256 * 2);       // 33.6 MB
  short* W1b  = (short*)alloc(256 * 384 * 2);
  short* W2b  = (short*)alloc(256 * 256 * 2);
  int*   idx  = (int*)alloc((size_t)3 * B_ * N_ * 4);
  float* wts  = (float*)alloc((size_t)3 * B_ * N_ * 4);
  float* part = (float*)alloc(8 * 8 * 16 * 2 * 4);
  float* fin1 = (float*)alloc(64 * 2 * 4);
  float* fin2 = (float*)alloc(64 * 2 * 4);
  short* y2 = (short*)x0T;  // x0T dead after gemm1; reuse for y2

  k_wcast<<<384, 256, 0, stream>>>(W1, W2, W1b, W2b);
  k_transpose_cast<<<dim3(M_ / 32, CC_ / 32, B_), 256, 0, stream>>>(cf, FT, CC_, M_, CC_, 0);
  k_transpose_cast<<<dim3(N_ / 32, CP_ / 32, B_), 256, 0, stream>>>(pf, x0T, CP_, N_, CIN_, 256);
  k_knn<<<dim3(N_ / 64, B_), 256, 0, stream>>>(pc, cc, idx, wts);
  k_interp<<<dim3(N_ / 8, B_), 256, 0, stream>>>(FT, idx, wts, x0T);
  k_gemm<<<dim3(2, N_ / 128, B_), 256, 0, stream>>>(W1b, x0T, b1, y1, CIN_);
  k_gnstats<<<dim3(16, B_), 256, 0, stream>>>(y1, part);
  k_gnfinal<<<1, 64, 0, stream>>>(part, fin1);
  k_gnapply<<<2048, 256, 0, stream>>>(y1, fin1, g1w, g1b);
  k_gemm<<<dim3(2, N_ / 128, B_), 256, 0, stream>>>(W2b, y1, b2, y2, 256);
  k_gnstats<<<dim3(16, B_), 256, 0, stream>>>(y2, part);
  k_gnfinal<<<1, 64, 0, stream>>>(part, fin2);
  k_gnapply_out<<<dim3(N_ / 64, 4, B_), 256, 0, stream>>>(y2, fin2, g2w, g2b, out);
  k_tail<<<2048, 256, 0, stream>>>(pc, te, out);
}

// Round 4
// 213.564 us; speedup vs baseline: 1.9077x; 1.6236x over previous
//
#include <hip/hip_runtime.h>
#include <hip/hip_bf16.h>
#include <float.h>

#define B_ 8
#define N_ 8192
#define M_ 2048
#define CC_ 256
#define CP_ 128
#define CIN_ 384
#define GRP_ 8

typedef __attribute__((ext_vector_type(8))) short short8;
typedef __attribute__((ext_vector_type(4))) short short4v;
typedef __attribute__((ext_vector_type(4))) float f32x4;

static __device__ __forceinline__ float bf2f(unsigned short u) {
  union { unsigned int i; float f; } v; v.i = ((unsigned int)u) << 16; return v.f;
}
static __device__ __forceinline__ unsigned short f2bf(float f) {
  union { float f; unsigned int i; } v; v.f = f;
  unsigned int u = v.i;
  unsigned int r = (u + 0x7FFFu + ((u >> 16) & 1u)) >> 16;
  return (unsigned short)r;
}
static __device__ __forceinline__ void gload16(const void* g, void* l) {
  __builtin_amdgcn_global_load_lds(
      (const __attribute__((address_space(1))) void*)g,
      (__attribute__((address_space(3))) void*)l, 16, 0, 0);
}

// ---------------- weight cast ----------------
__global__ void k_wcast(const float* __restrict__ W1, const float* __restrict__ W2,
                        short* __restrict__ W1b, short* __restrict__ W2b) {
  int i = blockIdx.x * blockDim.x + threadIdx.x;
  if (i < 256 * CIN_) W1b[i] = (short)f2bf(W1[i]);
  if (i < 256 * 256)  W2b[i] = (short)f2bf(W2[i]);
}

// ---------------- transpose + cast: [b][C][Nn] f32 -> [b][Nn][RS] bf16 at col off ----
__global__ __launch_bounds__(256) void k_transpose_cast(
    const float* __restrict__ in, short* __restrict__ out,
    int C, int Nn, int RS, int coff) {
  __shared__ float tile[32][33];
  int b = blockIdx.z;
  const float* inb = in + (size_t)b * C * Nn;
  short* outb = out + (size_t)b * Nn * RS;
  int n0 = blockIdx.x * 32, c0 = blockIdx.y * 32;
  int tx = threadIdx.x & 31, ty = threadIdx.x >> 5;
#pragma unroll
  for (int i = 0; i < 32; i += 8)
    tile[ty + i][tx] = inb[(size_t)(c0 + ty + i) * Nn + n0 + tx];
  __syncthreads();
#pragma unroll
  for (int i = 0; i < 32; i += 8)
    outb[(size_t)(n0 + ty + i) * RS + coff + c0 + tx] = (short)f2bf(tile[tx][ty + i]);
}

// ---------------- 3-NN: 4-way M-chunked, branchless top-3, EXACT fp32 distances ----
__global__ __launch_bounds__(256) void k_knn(
    const float* __restrict__ pc, const float* __restrict__ cc,
    int* __restrict__ idx, float* __restrict__ wts) {
  __shared__ __align__(16) float4 ctr[M_];     // 32 KB
  __shared__ float md[4][3][64];
  __shared__ int   mi[4][3][64];
  int b = blockIdx.y;
  int t = threadIdx.x;
  const float* ccb = cc + (size_t)b * 3 * M_;
  for (int i = t; i < M_; i += 256) {
    float x = ccb[i], y = ccb[M_ + i], z = ccb[2 * M_ + i];
    ctr[i] = make_float4(x, y, z, x * x + y * y + z * z);
  }
  __syncthreads();
  int wv = t >> 6, lane = t & 63;
  int n = blockIdx.x * 64 + lane;
  const float* pcb = pc + (size_t)b * 3 * N_;
  float px = pcb[n], py = pcb[N_ + n], pz = pcb[2 * N_ + n];
  float p2 = px * px + py * py + pz * pz;
  float d0 = FLT_MAX, d1 = FLT_MAX, d2 = FLT_MAX;
  int i0 = 0, i1 = 0, i2 = 0;
  const float4* C = ctr + wv * 512;
  int mbase = wv * 512;
#pragma unroll 8
  for (int m = 0; m < 512; ++m) {
    float4 c = C[m];                           // wave-uniform -> LDS broadcast
    float dot = px * c.x;
    dot = __builtin_fmaf(py, c.y, dot);
    dot = __builtin_fmaf(pz, c.z, dot);
    float d = __builtin_fmaf(-2.f, dot, c.w) + p2;
    int im = mbase + m;
    bool c0 = d < d0, c1 = d < d1, c2 = d < d2;
    i2 = c2 ? (c1 ? i1 : im) : i2;             // uses OLD i1
    i1 = c1 ? (c0 ? i0 : im) : i1;             // uses OLD i0
    i0 = c0 ? im : i0;
    d2 = fminf(fmaxf(d, d1), d2);              // uses OLD d1
    d1 = __builtin_amdgcn_fmed3f(d, d0, d1);   // uses OLD d0
    d0 = fminf(d, d0);
  }
  md[wv][0][lane] = d0; mi[wv][0][lane] = i0;
  md[wv][1][lane] = d1; mi[wv][1][lane] = i1;
  md[wv][2][lane] = d2; mi[wv][2][lane] = i2;
  __syncthreads();
  if (t < 64) {
#pragma unroll
    for (int w = 1; w < 4; ++w) {
#pragma unroll
      for (int j = 0; j < 3; ++j) {
        float d = md[w][j][t]; int im = mi[w][j][t];
        bool c0 = d < d0, c1 = d < d1, c2 = d < d2;
        i2 = c2 ? (c1 ? i1 : im) : i2;
        i1 = c1 ? (c0 ? i0 : im) : i1;
        i0 = c0 ? im : i0;
        d2 = fminf(fmaxf(d, d1), d2);
        d1 = __builtin_amdgcn_fmed3f(d, d0, d1);
        d0 = fminf(d, d0);
      }
    }
    float w0 = 1.f / (d0 + 1e-8f), w1 = 1.f / (d1 + 1e-8f), w2 = 1.f / (d2 + 1e-8f);
    float inv = 1.f / (w0 + w1 + w2);
    int bn = b * N_ + blockIdx.x * 64 + t;
    wts[bn] = w0 * inv; wts[B_ * N_ + bn] = w1 * inv; wts[2 * B_ * N_ + bn] = w2 * inv;
    idx[bn] = i0;
    idx[B_ * N_ + bn] = i1;
    idx[2 * B_ * N_ + bn] = i2;
  }
}

// ---------------- gather + weighted sum -> x0T[b][n][0..256) ----------------
__global__ __launch_bounds__(256) void k_interp(
    const short* __restrict__ FT, const int* __restrict__ idx,
    const float* __restrict__ wts, short* __restrict__ x0T) {
  int b = blockIdx.y;
  int t = threadIdx.x;
  int nl = t >> 5, cch = (t & 31) * 8;
  int n = blockIdx.x * 8 + nl;
  int bn = b * N_ + n;
  int i0 = idx[bn], i1 = idx[B_ * N_ + bn], i2 = idx[2 * B_ * N_ + bn];
  float w0 = wts[bn], w1 = wts[B_ * N_ + bn], w2 = wts[2 * B_ * N_ + bn];
  const short* Fb = FT + (size_t)b * M_ * CC_;
  short8 f0 = *(const short8*)(Fb + (size_t)i0 * CC_ + cch);
  short8 f1 = *(const short8*)(Fb + (size_t)i1 * CC_ + cch);
  short8 f2 = *(const short8*)(Fb + (size_t)i2 * CC_ + cch);
  short8 r;
#pragma unroll
  for (int e = 0; e < 8; ++e) {
    float v = w0 * bf2f((unsigned short)f0[e]) + w1 * bf2f((unsigned short)f1[e]) +
              w2 * bf2f((unsigned short)f2[e]);
    r[e] = (short)f2bf(v);
  }
  *(short8*)(x0T + (size_t)bn * CIN_ + cch) = r;
}

// ---------------- bf16 MFMA GEMM + fused GN partial stats ----------------
// Y[b][n][o] = W[o][:] . X[b][n][:] + bias[o]; also writes per-(group, ntile)
// partial sum/sumsq (fp32, pre-rounding) for GroupNorm.
// part layout: [b*8+grp][64 ntiles][2]
__global__ __launch_bounds__(256) void k_gemm(
    const short* __restrict__ Wb, const short* __restrict__ Xb,
    const float* __restrict__ bias, short* __restrict__ Yb,
    float* __restrict__ part, int K) {
  __shared__ __align__(16) short sW[128 * 64];   // 16 KB
  __shared__ __align__(16) short sX[128 * 64];   // 16 KB
  int b = blockIdx.z;
  int otile = blockIdx.x * 128;
  int ntile = blockIdx.y * 128;
  int t = threadIdx.x;
  int wv = t >> 6, lane = t & 63;
  int wr = wv >> 1, wc = wv & 1;
  int fr = lane & 15;     // fragment row
  int g = lane >> 4;      // k-subchunk selector
  f32x4 acc[4][4] = {};
  const short* Wp = Wb + (size_t)otile * K;
  const short* Xp = Xb + ((size_t)b * N_ + ntile) * K;
  for (int k0 = 0; k0 < K; k0 += 64) {
#pragma unroll
    for (int j = 0; j < 4; ++j) {
      int s = j * 256 + t;          // slot 0..1023, 16B each
      int row = s >> 3;             // 8 slots (128B) per row
      int kc = (s & 7) ^ (row & 7); // inverse-swizzled source chunk
      gload16(Wp + (size_t)row * K + k0 + kc * 8, sW + j * 2048 + wv * 512);
      gload16(Xp + (size_t)row * K + k0 + kc * 8, sX + j * 2048 + wv * 512);
    }
    __syncthreads();
#pragma unroll
    for (int h = 0; h < 2; ++h) {
      short8 af[4], bfr[4];
#pragma unroll
      for (int m = 0; m < 4; ++m) {
        int ra = wr * 64 + m * 16 + fr;
        af[m] = *(const short8*)(sW + ra * 64 + (((h * 4 + g) ^ (ra & 7)) << 3));
        int rb = wc * 64 + m * 16 + fr;
        bfr[m] = *(const short8*)(sX + rb * 64 + (((h * 4 + g) ^ (rb & 7)) << 3));
      }
#pragma unroll
      for (int m = 0; m < 4; ++m)
#pragma unroll
        for (int nn = 0; nn < 4; ++nn)
          acc[m][nn] = __builtin_amdgcn_mfma_f32_16x16x32_bf16(af[m], bfr[nn], acc[m][nn], 0, 0, 0);
    }
    __syncthreads();
  }
  // epilogue: store + per-lane GN partials (m<2 -> local group wr*2, m>=2 -> wr*2+1)
  float s01 = 0.f, ss01 = 0.f, s23 = 0.f, ss23 = 0.f;
#pragma unroll
  for (int m = 0; m < 4; ++m) {
    int o = otile + wr * 64 + m * 16 + g * 4;
    float4 bi = *(const float4*)(bias + o);
#pragma unroll
    for (int nn = 0; nn < 4; ++nn) {
      int n = ntile + wc * 64 + nn * 16 + fr;
      float v0 = acc[m][nn][0] + bi.x;
      float v1 = acc[m][nn][1] + bi.y;
      float v2 = acc[m][nn][2] + bi.z;
      float v3 = acc[m][nn][3] + bi.w;
      if (m < 2) { s01 += v0 + v1 + v2 + v3; ss01 += v0*v0 + v1*v1 + v2*v2 + v3*v3; }
      else       { s23 += v0 + v1 + v2 + v3; ss23 += v0*v0 + v1*v1 + v2*v2 + v3*v3; }
      short4v sv;
      sv[0] = (short)f2bf(v0);
      sv[1] = (short)f2bf(v1);
      sv[2] = (short)f2bf(v2);
      sv[3] = (short)f2bf(v3);
      *(short4v*)(Yb + ((size_t)b * N_ + n) * 256 + o) = sv;
    }
  }
#pragma unroll
  for (int off = 32; off > 0; off >>= 1) {
    s01 += __shfl_down(s01, off);
    ss01 += __shfl_down(ss01, off);
    s23 += __shfl_down(s23, off);
    ss23 += __shfl_down(ss23, off);
  }
  float* wred = (float*)sW;   // LDS reuse (k-loop done, post-barrier)
  if (lane == 0) {
    wred[wv * 4 + 0] = s01; wred[wv * 4 + 1] = ss01;
    wred[wv * 4 + 2] = s23; wred[wv * 4 + 3] = ss23;
  }
  __syncthreads();
  if (t < 8) {
    int gl = t >> 1, sel = t & 1;                 // local group 0..3, sum/sumsq
    int wrn = gl >> 1;                            // which wr produced it
    int id = (gl & 1) * 2 + sel;                  // s01/ss01 vs s23/ss23
    float v = wred[(wrn * 2 + 0) * 4 + id] + wred[(wrn * 2 + 1) * 4 + id];
    part[(((size_t)b * 8 + blockIdx.x * 4 + gl) * 64 + blockIdx.y) * 2 + sel] = v;
  }
}

__global__ void k_gnfinal(const float* __restrict__ part, float* __restrict__ fin) {
  int t = threadIdx.x;  // 64 = B*G
  float s = 0.f, ss = 0.f;
  for (int j = 0; j < 64; ++j) {
    s += part[((size_t)t * 64 + j) * 2];
    ss += part[((size_t)t * 64 + j) * 2 + 1];
  }
  const float cnt = 32.f * 8192.f;
  float mean = s / cnt;
  float var = ss / cnt - mean * mean;
  fin[t * 2] = mean;
  fin[t * 2 + 1] = rsqrtf(var + 1e-5f);
}

// ---------------- GN + swish in place (bf16 [b][n][256]) ----------------
__global__ __launch_bounds__(256) void k_gnapply(short* __restrict__ Y,
                                                 const float* __restrict__ fin,
                                                 const float* __restrict__ gw,
                                                 const float* __restrict__ gb) {
  unsigned int* Yd = (unsigned int*)Y;
  int total = B_ * N_ * 128;
  for (int i = blockIdx.x * blockDim.x + threadIdx.x; i < total;
       i += gridDim.x * blockDim.x) {
    int o2 = i & 127;
    int b = i >> 20;
    int g = o2 >> 4;
    float mean = fin[(b * 8 + g) * 2], rstd = fin[(b * 8 + g) * 2 + 1];
    unsigned int v = Yd[i];
    int o = o2 * 2;
    float a = bf2f((unsigned short)(v & 0xFFFF));
    float c = bf2f((unsigned short)(v >> 16));
    a = (a - mean) * rstd * gw[o] + gb[o];
    c = (c - mean) * rstd * gw[o + 1] + gb[o + 1];
    a = a / (1.f + __expf(-a));
    c = c / (1.f + __expf(-c));
    Yd[i] = (unsigned int)f2bf(a) | ((unsigned int)f2bf(c) << 16);
  }
}

// ---------------- GN + swish + transpose -> out [b][o][n] f32 ----------------
__global__ __launch_bounds__(256) void k_gnapply_out(
    const short* __restrict__ Y, const float* __restrict__ fin,
    const float* __restrict__ gw, const float* __restrict__ gb,
    float* __restrict__ out) {
  __shared__ float tile[64][65];
  int b = blockIdx.z;
  int n0 = blockIdx.x * 64, o0 = blockIdx.y * 64;
  int t = threadIdx.x;
  int row = t >> 5, dcol = t & 31;
  const unsigned int* Yd = (const unsigned int*)(Y + (size_t)b * N_ * 256);
  int o = o0 + dcol * 2;
  int g = o >> 5;
  float mean = fin[(b * 8 + g) * 2], rstd = fin[(b * 8 + g) * 2 + 1];
  float w0 = gw[o], w1 = gw[o + 1], bb0 = gb[o], bb1 = gb[o + 1];
#pragma unroll
  for (int p = 0; p < 8; ++p) {
    int n = n0 + p * 8 + row;
    unsigned int v = Yd[(size_t)n * 128 + (o0 >> 1) + dcol];
    float a = bf2f((unsigned short)(v & 0xFFFF));
    float c = bf2f((unsigned short)(v >> 16));
    a = (a - mean) * rstd * w0 + bb0; a = a / (1.f + __expf(-a));
    c = (c - mean) * rstd * w1 + bb1; c = c / (1.f + __expf(-c));
    tile[p * 8 + row][dcol * 2] = a;
    tile[p * 8 + row][dcol * 2 + 1] = c;
  }
  __syncthreads();
  int ol = t >> 2, nch = (t & 3) * 16;
  float* ob = out + ((size_t)(b * 256 + o0 + ol)) * N_ + n0 + nch;
#pragma unroll
  for (int c4 = 0; c4 < 16; c4 += 4) {
    float4 v4;
    v4.x = tile[nch + c4 + 0][ol];
    v4.y = tile[nch + c4 + 1][ol];
    v4.z = tile[nch + c4 + 2][ol];
    v4.w = tile[nch + c4 + 3][ol];
    *(float4*)(ob + c4) = v4;
  }
}

// ---------------- tail: coords copy + time_emb broadcast ----------------
__global__ void k_tail(const float* __restrict__ pc, const float* __restrict__ te,
                       float* __restrict__ out) {
  int total = 196608 + B_ * 64 * N_;
  for (int i = blockIdx.x * blockDim.x + threadIdx.x; i < total;
       i += gridDim.x * blockDim.x) {
    if (i < 196608) {
      out[16777216 + i] = pc[i];
    } else {
      int j = i - 196608;
      int bd = j >> 13;
      out[16973824 + j] = te[bd];
    }
  }
}

extern "C" void kernel_launch(void* const* d_in, const int* in_sizes, int n_in,
                              void* d_out, int out_size, void* d_ws, size_t ws_size,
                              hipStream_t stream) {
  const float* pc  = (const float*)d_in[0];
  const float* cc  = (const float*)d_in[1];
  const float* cf  = (const float*)d_in[2];
  const float* pf  = (const float*)d_in[3];
  const float* te  = (const float*)d_in[4];
  const float* W1  = (const float*)d_in[5];
  const float* b1  = (const float*)d_in[6];
  const float* g1w = (const float*)d_in[7];
  const float* g1b = (const float*)d_in[8];
  const float* W2  = (const float*)d_in[9];
  const float* b2  = (const float*)d_in[10];
  const float* g2w = (const float*)d_in[11];
  const float* g2b = (const float*)d_in[12];
  float* out = (float*)d_out;

  char* ws = (char*)d_ws;
  size_t off = 0;
  auto alloc = [&](size_t bytes) {
    char* p = ws + off;
    off += (bytes + 255) & ~(size_t)255;
    return p;
  };
  short* FT   = (short*)alloc((size_t)B_ * M_ * CC_ * 2);       // 8.4 MB
  short* x0T  = (short*)alloc((size_t)B_ * N_ * CIN_ * 2);      // 50.3 MB
  short* y1   = (short*)alloc((size_t)B_ * N_ * 256 * 2);       // 33.6 MB
  short* W1b  = (short*)alloc(256 * 384 * 2);
  short* W2b  = (short*)alloc(256 * 256 * 2);
  int*   idx  = (int*)alloc((size_t)3 * B_ * N_ * 4);
  float* wts  = (float*)alloc((size_t)3 * B_ * N_ * 4);
  float* part1 = (float*)alloc(8 * 8 * 64 * 2 * 4);
  float* part2 = (float*)alloc(8 * 8 * 64 * 2 * 4);
  float* fin1 = (float*)alloc(64 * 2 * 4);
  float* fin2 = (float*)alloc(64 * 2 * 4);
  short* y2 = (short*)x0T;  // x0T dead after gemm1; reuse for y2

  k_wcast<<<384, 256, 0, stream>>>(W1, W2, W1b, W2b);
  k_transpose_cast<<<dim3(M_ / 32, CC_ / 32, B_), 256, 0, stream>>>(cf, FT, CC_, M_, CC_, 0);
  k_transpose_cast<<<dim3(N_ / 32, CP_ / 32, B_), 256, 0, stream>>>(pf, x0T, CP_, N_, CIN_, 256);
  k_knn<<<dim3(N_ / 64, B_), 256, 0, stream>>>(pc, cc, idx, wts);
  k_interp<<<dim3(N_ / 8, B_), 256, 0, stream>>>(FT, idx, wts, x0T);
  k_gemm<<<dim3(2, N_ / 128, B_), 256, 0, stream>>>(W1b, x0T, b1, y1, part1, CIN_);
  k_gnfinal<<<1, 64, 0, stream>>>(part1, fin1);
  k_gnapply<<<2048, 256, 0, stream>>>(y1, fin1, g1w, g1b);
  k_gemm<<<dim3(2, N_ / 128, B_), 256, 0, stream>>>(W2b, y1, b2, y2, part2, 256);
  k_gnfinal<<<1, 64, 0, stream>>>(part2, fin2);
  k_gnapply_out<<<dim3(N_ / 64, 4, B_), 256, 0, stream>>>(y2, fin2, g2w, g2b, out);
  k_tail<<<2048, 256, 0, stream>>>(pc, te, out);
}

// Round 5
// 203.814 us; speedup vs baseline: 1.9990x; 1.0478x over previous
//
#include <hip/hip_runtime.h>
#include <hip/hip_bf16.h>
#include <float.h>

#define B_ 8
#define N_ 8192
#define M_ 2048
#define CC_ 256
#define CP_ 128
#define CIN_ 384
#define GRP_ 8

typedef __attribute__((ext_vector_type(8))) short short8;
typedef __attribute__((ext_vector_type(4))) short short4v;
typedef __attribute__((ext_vector_type(4))) float f32x4;

static __device__ __forceinline__ float bf2f(unsigned short u) {
  union { unsigned int i; float f; } v; v.i = ((unsigned int)u) << 16; return v.f;
}
static __device__ __forceinline__ unsigned short f2bf(float f) {
  union { float f; unsigned int i; } v; v.f = f;
  unsigned int u = v.i;
  unsigned int r = (u + 0x7FFFu + ((u >> 16) & 1u)) >> 16;
  return (unsigned short)r;
}
static __device__ __forceinline__ void gload16(const void* g, void* l) {
  __builtin_amdgcn_global_load_lds(
      (const __attribute__((address_space(1))) void*)g,
      (__attribute__((address_space(3))) void*)l, 16, 0, 0);
}

// ---------------- prep: weight cast + both transpose-casts in one launch ----------------
// blocks [0,384): wcast; [384,4480): cf->FT; [4480,12672): pf->x0T cols 256..383
__global__ __launch_bounds__(256) void k_prep(
    const float* __restrict__ W1, const float* __restrict__ W2,
    short* __restrict__ W1b, short* __restrict__ W2b,
    const float* __restrict__ cf, short* __restrict__ FT,
    const float* __restrict__ pf, short* __restrict__ x0T) {
  __shared__ float tile[32][33];
  int bid = blockIdx.x;
  int t = threadIdx.x;
  if (bid < 384) {
    int i = bid * 256 + t;
    if (i < 256 * CIN_) W1b[i] = (short)f2bf(W1[i]);
    if (i < 256 * 256)  W2b[i] = (short)f2bf(W2[i]);
    return;
  }
  const float* in; short* out;
  int C, Nn, RS, coff, n0, c0, b;
  if (bid < 4480) {
    int q = bid - 384;             // x<64, y<8, b<8
    in = cf; out = FT; C = CC_; Nn = M_; RS = CC_; coff = 0;
    n0 = (q & 63) * 32; c0 = ((q >> 6) & 7) * 32; b = q >> 9;
  } else {
    int q = bid - 4480;            // x<256, y<4, b<8
    in = pf; out = x0T; C = CP_; Nn = N_; RS = CIN_; coff = 256;
    n0 = (q & 255) * 32; c0 = ((q >> 8) & 3) * 32; b = q >> 10;
  }
  const float* inb = in + (size_t)b * C * Nn;
  short* outb = out + (size_t)b * Nn * RS;
  int tx = t & 31, ty = t >> 5;
#pragma unroll
  for (int i = 0; i < 32; i += 8)
    tile[ty + i][tx] = inb[(size_t)(c0 + ty + i) * Nn + n0 + tx];
  __syncthreads();
#pragma unroll
  for (int i = 0; i < 32; i += 8)
    outb[(size_t)(n0 + ty + i) * RS + coff + c0 + tx] = (short)f2bf(tile[tx][ty + i]);
}

// ---------------- 3-NN: 4-way M-chunked, f64 packed-key top-3 (exact) ----------------
// key = double{hi = f32 bits of d, lo = center idx}: lex order (d, idx), exact.
__global__ __launch_bounds__(256) void k_knn(
    const float* __restrict__ pc, const float* __restrict__ cc,
    int* __restrict__ idx, float* __restrict__ wts) {
  __shared__ __align__(16) float4 ctr[M_];     // 32 KB
  __shared__ double mk[4][3][64];              // 6 KB
  int b = blockIdx.y;
  int t = threadIdx.x;
  const float* ccb = cc + (size_t)b * 3 * M_;
  for (int i = t; i < M_; i += 256) {
    float x = ccb[i], y = ccb[M_ + i], z = ccb[2 * M_ + i];
    ctr[i] = make_float4(x, y, z, x * x + y * y + z * z);
  }
  __syncthreads();
  int wv = t >> 6, lane = t & 63;
  int n = blockIdx.x * 64 + lane;
  const float* pcb = pc + (size_t)b * 3 * N_;
  float px = pcb[n], py = pcb[N_ + n], pz = pcb[2 * N_ + n];
  float p2 = px * px + py * py + pz * pz;
  double k0 = __hiloint2double(0x7F7FFFFF, 0);
  double k1 = k0, k2 = k0;
  const float4* C = ctr + wv * 512;
  int mbase = wv * 512;
#pragma unroll 8
  for (int m = 0; m < 512; ++m) {
    float4 c = C[m];                           // wave-uniform -> LDS broadcast
    float dot = px * c.x;
    dot = __builtin_fmaf(py, c.y, dot);
    dot = __builtin_fmaf(pz, c.z, dot);
    float d = __builtin_fmaf(-2.f, dot, c.w) + p2;
    double key = __hiloint2double(__float_as_int(d), mbase + m);
    double n0 = fmin(key, k0);
    double n1 = fmin(fmax(key, k0), k1);
    double n2 = fmin(fmax(key, k1), k2);
    k0 = n0; k1 = n1; k2 = n2;
  }
  mk[wv][0][lane] = k0; mk[wv][1][lane] = k1; mk[wv][2][lane] = k2;
  __syncthreads();
  if (t < 64) {
#pragma unroll
    for (int w = 1; w < 4; ++w) {
#pragma unroll
      for (int j = 0; j < 3; ++j) {
        double key = mk[w][j][t];
        double n0 = fmin(key, k0);
        double n1 = fmin(fmax(key, k0), k1);
        double n2 = fmin(fmax(key, k1), k2);
        k0 = n0; k1 = n1; k2 = n2;
      }
    }
    float d0 = __int_as_float(__double2hiint(k0));
    float d1 = __int_as_float(__double2hiint(k1));
    float d2 = __int_as_float(__double2hiint(k2));
    float w0 = 1.f / (d0 + 1e-8f), w1 = 1.f / (d1 + 1e-8f), w2 = 1.f / (d2 + 1e-8f);
    float inv = 1.f / (w0 + w1 + w2);
    int bn = b * N_ + blockIdx.x * 64 + t;
    wts[bn] = w0 * inv; wts[B_ * N_ + bn] = w1 * inv; wts[2 * B_ * N_ + bn] = w2 * inv;
    idx[bn] = __double2loint(k0);
    idx[B_ * N_ + bn] = __double2loint(k1);
    idx[2 * B_ * N_ + bn] = __double2loint(k2);
  }
}

// ---------------- gather + weighted sum -> x0T[b][n][0..256) ----------------
__global__ __launch_bounds__(256) void k_interp(
    const short* __restrict__ FT, const int* __restrict__ idx,
    const float* __restrict__ wts, short* __restrict__ x0T) {
  int b = blockIdx.y;
  int t = threadIdx.x;
  int nl = t >> 5, cch = (t & 31) * 8;
  int n = blockIdx.x * 8 + nl;
  int bn = b * N_ + n;
  int i0 = idx[bn], i1 = idx[B_ * N_ + bn], i2 = idx[2 * B_ * N_ + bn];
  float w0 = wts[bn], w1 = wts[B_ * N_ + bn], w2 = wts[2 * B_ * N_ + bn];
  const short* Fb = FT + (size_t)b * M_ * CC_;
  short8 f0 = *(const short8*)(Fb + (size_t)i0 * CC_ + cch);
  short8 f1 = *(const short8*)(Fb + (size_t)i1 * CC_ + cch);
  short8 f2 = *(const short8*)(Fb + (size_t)i2 * CC_ + cch);
  short8 r;
#pragma unroll
  for (int e = 0; e < 8; ++e) {
    float v = w0 * bf2f((unsigned short)f0[e]) + w1 * bf2f((unsigned short)f1[e]) +
              w2 * bf2f((unsigned short)f2[e]);
    r[e] = (short)f2bf(v);
  }
  *(short8*)(x0T + (size_t)bn * CIN_ + cch) = r;
}

// ---------------- bf16 MFMA GEMM + fused GN partial stats ----------------
// part layout: [b*8+grp][64 ntiles][2]
__global__ __launch_bounds__(256) void k_gemm(
    const short* __restrict__ Wb, const short* __restrict__ Xb,
    const float* __restrict__ bias, short* __restrict__ Yb,
    float* __restrict__ part, int K) {
  __shared__ __align__(16) short sW[128 * 64];   // 16 KB
  __shared__ __align__(16) short sX[128 * 64];   // 16 KB
  int b = blockIdx.z;
  int otile = blockIdx.x * 128;
  int ntile = blockIdx.y * 128;
  int t = threadIdx.x;
  int wv = t >> 6, lane = t & 63;
  int wr = wv >> 1, wc = wv & 1;
  int fr = lane & 15;     // fragment row
  int g = lane >> 4;      // k-subchunk selector
  f32x4 acc[4][4] = {};
  const short* Wp = Wb + (size_t)otile * K;
  const short* Xp = Xb + ((size_t)b * N_ + ntile) * K;
  for (int k0 = 0; k0 < K; k0 += 64) {
#pragma unroll
    for (int j = 0; j < 4; ++j) {
      int s = j * 256 + t;          // slot 0..1023, 16B each
      int row = s >> 3;             // 8 slots (128B) per row
      int kc = (s & 7) ^ (row & 7); // inverse-swizzled source chunk
      gload16(Wp + (size_t)row * K + k0 + kc * 8, sW + j * 2048 + wv * 512);
      gload16(Xp + (size_t)row * K + k0 + kc * 8, sX + j * 2048 + wv * 512);
    }
    __syncthreads();
#pragma unroll
    for (int h = 0; h < 2; ++h) {
      short8 af[4], bfr[4];
#pragma unroll
      for (int m = 0; m < 4; ++m) {
        int ra = wr * 64 + m * 16 + fr;
        af[m] = *(const short8*)(sW + ra * 64 + (((h * 4 + g) ^ (ra & 7)) << 3));
        int rb = wc * 64 + m * 16 + fr;
        bfr[m] = *(const short8*)(sX + rb * 64 + (((h * 4 + g) ^ (rb & 7)) << 3));
      }
#pragma unroll
      for (int m = 0; m < 4; ++m)
#pragma unroll
        for (int nn = 0; nn < 4; ++nn)
          acc[m][nn] = __builtin_amdgcn_mfma_f32_16x16x32_bf16(af[m], bfr[nn], acc[m][nn], 0, 0, 0);
    }
    __syncthreads();
  }
  // epilogue: store + per-lane GN partials (m<2 -> local group wr*2, m>=2 -> wr*2+1)
  float s01 = 0.f, ss01 = 0.f, s23 = 0.f, ss23 = 0.f;
#pragma unroll
  for (int m = 0; m < 4; ++m) {
    int o = otile + wr * 64 + m * 16 + g * 4;
    float4 bi = *(const float4*)(bias + o);
#pragma unroll
    for (int nn = 0; nn < 4; ++nn) {
      int n = ntile + wc * 64 + nn * 16 + fr;
      float v0 = acc[m][nn][0] + bi.x;
      float v1 = acc[m][nn][1] + bi.y;
      float v2 = acc[m][nn][2] + bi.z;
      float v3 = acc[m][nn][3] + bi.w;
      if (m < 2) { s01 += v0 + v1 + v2 + v3; ss01 += v0*v0 + v1*v1 + v2*v2 + v3*v3; }
      else       { s23 += v0 + v1 + v2 + v3; ss23 += v0*v0 + v1*v1 + v2*v2 + v3*v3; }
      short4v sv;
      sv[0] = (short)f2bf(v0);
      sv[1] = (short)f2bf(v1);
      sv[2] = (short)f2bf(v2);
      sv[3] = (short)f2bf(v3);
      *(short4v*)(Yb + ((size_t)b * N_ + n) * 256 + o) = sv;
    }
  }
#pragma unroll
  for (int off = 32; off > 0; off >>= 1) {
    s01 += __shfl_down(s01, off);
    ss01 += __shfl_down(ss01, off);
    s23 += __shfl_down(s23, off);
    ss23 += __shfl_down(ss23, off);
  }
  float* wred = (float*)sW;   // LDS reuse (k-loop done, post-barrier)
  if (lane == 0) {
    wred[wv * 4 + 0] = s01; wred[wv * 4 + 1] = ss01;
    wred[wv * 4 + 2] = s23; wred[wv * 4 + 3] = ss23;
  }
  __syncthreads();
  if (t < 8) {
    int gl = t >> 1, sel = t & 1;                 // local group 0..3, sum/sumsq
    int wrn = gl >> 1;                            // which wr produced it
    int id = (gl & 1) * 2 + sel;                  // s01/ss01 vs s23/ss23
    float v = wred[(wrn * 2 + 0) * 4 + id] + wred[(wrn * 2 + 1) * 4 + id];
    part[(((size_t)b * 8 + blockIdx.x * 4 + gl) * 64 + blockIdx.y) * 2 + sel] = v;
  }
}

// ---------------- GN + swish in place (bf16 [b][n][256]), stats finalized in-block ----
__global__ __launch_bounds__(256) void k_gnapply(short* __restrict__ Y,
                                                 const float* __restrict__ part,
                                                 const float* __restrict__ gw,
                                                 const float* __restrict__ gb) {
  __shared__ float fs[128];
  int t = threadIdx.x;
  if (t < 64) {
    float s = 0.f, ss = 0.f;
    for (int j = 0; j < 64; ++j) {
      s += part[((size_t)t * 64 + j) * 2];
      ss += part[((size_t)t * 64 + j) * 2 + 1];
    }
    const float cnt = 32.f * 8192.f;
    float mean = s / cnt;
    float var = ss / cnt - mean * mean;
    fs[t * 2] = mean;
    fs[t * 2 + 1] = rsqrtf(var + 1e-5f);
  }
  __syncthreads();
  unsigned int* Yd = (unsigned int*)Y;
  int total = B_ * N_ * 128;
  for (int i = blockIdx.x * blockDim.x + t; i < total;
       i += gridDim.x * blockDim.x) {
    int o2 = i & 127;
    int b = i >> 20;
    int g = o2 >> 4;
    float mean = fs[(b * 8 + g) * 2], rstd = fs[(b * 8 + g) * 2 + 1];
    unsigned int v = Yd[i];
    int o = o2 * 2;
    float a = bf2f((unsigned short)(v & 0xFFFF));
    float c = bf2f((unsigned short)(v >> 16));
    a = (a - mean) * rstd * gw[o] + gb[o];
    c = (c - mean) * rstd * gw[o + 1] + gb[o + 1];
    a = a / (1.f + __expf(-a));
    c = c / (1.f + __expf(-c));
    Yd[i] = (unsigned int)f2bf(a) | ((unsigned int)f2bf(c) << 16);
  }
}

// ---------------- GN + swish + transpose -> out [b][o][n] f32, stats in-block ----------
__global__ __launch_bounds__(256) void k_gnapply_out(
    const short* __restrict__ Y, const float* __restrict__ part,
    const float* __restrict__ gw, const float* __restrict__ gb,
    float* __restrict__ out) {
  __shared__ float tile[64][65];
  __shared__ float fs[16];
  int b = blockIdx.z;
  int t = threadIdx.x;
  if (t < 8) {
    float s = 0.f, ss = 0.f;
    for (int j = 0; j < 64; ++j) {
      s += part[(((size_t)b * 8 + t) * 64 + j) * 2];
      ss += part[(((size_t)b * 8 + t) * 64 + j) * 2 + 1];
    }
    const float cnt = 32.f * 8192.f;
    float mean = s / cnt;
    float var = ss / cnt - mean * mean;
    fs[t * 2] = mean;
    fs[t * 2 + 1] = rsqrtf(var + 1e-5f);
  }
  __syncthreads();
  int n0 = blockIdx.x * 64, o0 = blockIdx.y * 64;
  int row = t >> 5, dcol = t & 31;
  const unsigned int* Yd = (const unsigned int*)(Y + (size_t)b * N_ * 256);
  int o = o0 + dcol * 2;
  int g = o >> 5;
  float mean = fs[g * 2], rstd = fs[g * 2 + 1];
  float w0 = gw[o], w1 = gw[o + 1], bb0 = gb[o], bb1 = gb[o + 1];
#pragma unroll
  for (int p = 0; p < 8; ++p) {
    int n = n0 + p * 8 + row;
    unsigned int v = Yd[(size_t)n * 128 + (o0 >> 1) + dcol];
    float a = bf2f((unsigned short)(v & 0xFFFF));
    float c = bf2f((unsigned short)(v >> 16));
    a = (a - mean) * rstd * w0 + bb0; a = a / (1.f + __expf(-a));
    c = (c - mean) * rstd * w1 + bb1; c = c / (1.f + __expf(-c));
    tile[p * 8 + row][dcol * 2] = a;
    tile[p * 8 + row][dcol * 2 + 1] = c;
  }
  __syncthreads();
  int ol = t >> 2, nch = (t & 3) * 16;
  float* ob = out + ((size_t)(b * 256 + o0 + ol)) * N_ + n0 + nch;
#pragma unroll
  for (int c4 = 0; c4 < 16; c4 += 4) {
    float4 v4;
    v4.x = tile[nch + c4 + 0][ol];
    v4.y = tile[nch + c4 + 1][ol];
    v4.z = tile[nch + c4 + 2][ol];
    v4.w = tile[nch + c4 + 3][ol];
    *(float4*)(ob + c4) = v4;
  }
}

// ---------------- tail: coords copy + time_emb broadcast ----------------
__global__ void k_tail(const float* __restrict__ pc, const float* __restrict__ te,
                       float* __restrict__ out) {
  int total = 196608 + B_ * 64 * N_;
  for (int i = blockIdx.x * blockDim.x + threadIdx.x; i < total;
       i += gridDim.x * blockDim.x) {
    if (i < 196608) {
      out[16777216 + i] = pc[i];
    } else {
      int j = i - 196608;
      int bd = j >> 13;
      out[16973824 + j] = te[bd];
    }
  }
}

extern "C" void kernel_launch(void* const* d_in, const int* in_sizes, int n_in,
                              void* d_out, int out_size, void* d_ws, size_t ws_size,
                              hipStream_t stream) {
  const float* pc  = (const float*)d_in[0];
  const float* cc  = (const float*)d_in[1];
  const float* cf  = (const float*)d_in[2];
  const float* pf  = (const float*)d_in[3];
  const float* te  = (const float*)d_in[4];
  const float* W1  = (const float*)d_in[5];
  const float* b1  = (const float*)d_in[6];
  const float* g1w = (const float*)d_in[7];
  const float* g1b = (const float*)d_in[8];
  const float* W2  = (const float*)d_in[9];
  const float* b2  = (const float*)d_in[10];
  const float* g2w = (const float*)d_in[11];
  const float* g2b = (const float*)d_in[12];
  float* out = (float*)d_out;

  char* ws = (char*)d_ws;
  size_t off = 0;
  auto alloc = [&](size_t bytes) {
    char* p = ws + off;
    off += (bytes + 255) & ~(size_t)255;
    return p;
  };
  short* FT   = (short*)alloc((size_t)B_ * M_ * CC_ * 2);       // 8.4 MB
  short* x0T  = (short*)alloc((size_t)B_ * N_ * CIN_ * 2);      // 50.3 MB
  short* y1   = (short*)alloc((size_t)B_ * N_ * 256 * 2);       // 33.6 MB
  short* W1b  = (short*)alloc(256 * 384 * 2);
  short* W2b  = (short*)alloc(256 * 256 * 2);
  int*   idx  = (int*)alloc((size_t)3 * B_ * N_ * 4);
  float* wts  = (float*)alloc((size_t)3 * B_ * N_ * 4);
  float* part1 = (float*)alloc(8 * 8 * 64 * 2 * 4);
  float* part2 = (float*)alloc(8 * 8 * 64 * 2 * 4);
  short* y2 = (short*)x0T;  // x0T dead after gemm1; reuse for y2

  k_prep<<<12672, 256, 0, stream>>>(W1, W2, W1b, W2b, cf, FT, pf, x0T);
  k_knn<<<dim3(N_ / 64, B_), 256, 0, stream>>>(pc, cc, idx, wts);
  k_interp<<<dim3(N_ / 8, B_), 256, 0, stream>>>(FT, idx, wts, x0T);
  k_gemm<<<dim3(2, N_ / 128, B_), 256, 0, stream>>>(W1b, x0T, b1, y1, part1, CIN_);
  k_gnapply<<<2048, 256, 0, stream>>>(y1, part1, g1w, g1b);
  k_gemm<<<dim3(2, N_ / 128, B_), 256, 0, stream>>>(W2b, y1, b2, y2, part2, 256);
  k_gnapply_out<<<dim3(N_ / 64, 4, B_), 256, 0, stream>>>(y2, part2, g2w, g2b, out);
  k_tail<<<2048, 256, 0, stream>>>(pc, te, out);
}

// Round 6
// 194.846 us; speedup vs baseline: 2.0910x; 1.0460x over previous
//
#include <hip/hip_runtime.h>
#include <hip/hip_bf16.h>
#include <float.h>

#define B_ 8
#define N_ 8192
#define M_ 2048
#define CC_ 256
#define CP_ 128
#define CIN_ 384
#define GRP_ 8

typedef __attribute__((ext_vector_type(8))) short short8;
typedef __attribute__((ext_vector_type(4))) short short4v;
typedef __attribute__((ext_vector_type(4))) float f32x4;

static __device__ __forceinline__ float bf2f(unsigned short u) {
  union { unsigned int i; float f; } v; v.i = ((unsigned int)u) << 16; return v.f;
}
static __device__ __forceinline__ unsigned short f2bf(float f) {
  union { float f; unsigned int i; } v; v.f = f;
  unsigned int u = v.i;
  unsigned int r = (u + 0x7FFFu + ((u >> 16) & 1u)) >> 16;
  return (unsigned short)r;
}
static __device__ __forceinline__ void gload16(const void* g, void* l) {
  __builtin_amdgcn_global_load_lds(
      (const __attribute__((address_space(1))) void*)g,
      (__attribute__((address_space(3))) void*)l, 16, 0, 0);
}

// ---------------- prep: weight cast + both transpose-casts in one launch ----------------
// blocks [0,384): wcast; [384,4480): cf->FT; [4480,12672): pf->x0T cols 256..383
__global__ __launch_bounds__(256) void k_prep(
    const float* __restrict__ W1, const float* __restrict__ W2,
    short* __restrict__ W1b, short* __restrict__ W2b,
    const float* __restrict__ cf, short* __restrict__ FT,
    const float* __restrict__ pf, short* __restrict__ x0T) {
  __shared__ float tile[32][33];
  int bid = blockIdx.x;
  int t = threadIdx.x;
  if (bid < 384) {
    int i = bid * 256 + t;
    if (i < 256 * CIN_) W1b[i] = (short)f2bf(W1[i]);
    if (i < 256 * 256)  W2b[i] = (short)f2bf(W2[i]);
    return;
  }
  const float* in; short* out;
  int C, Nn, RS, coff, n0, c0, b;
  if (bid < 4480) {
    int q = bid - 384;             // x<64, y<8, b<8
    in = cf; out = FT; C = CC_; Nn = M_; RS = CC_; coff = 0;
    n0 = (q & 63) * 32; c0 = ((q >> 6) & 7) * 32; b = q >> 9;
  } else {
    int q = bid - 4480;            // x<256, y<4, b<8
    in = pf; out = x0T; C = CP_; Nn = N_; RS = CIN_; coff = 256;
    n0 = (q & 255) * 32; c0 = ((q >> 8) & 3) * 32; b = q >> 10;
  }
  const float* inb = in + (size_t)b * C * Nn;
  short* outb = out + (size_t)b * Nn * RS;
  int tx = t & 31, ty = t >> 5;
#pragma unroll
  for (int i = 0; i < 32; i += 8)
    tile[ty + i][tx] = inb[(size_t)(c0 + ty + i) * Nn + n0 + tx];
  __syncthreads();
#pragma unroll
  for (int i = 0; i < 32; i += 8)
    outb[(size_t)(n0 + ty + i) * RS + coff + c0 + tx] = (short)f2bf(tile[tx][ty + i]);
}

// ---------------- 3-NN: 8-wave blocks, 8-way M-chunks, 2 pts/thread, f64 packed keys ----
// key = double{hi = f32 bits of d, lo = center idx}: lex order (d, idx), exact.
__global__ __launch_bounds__(512) void k_knn(
    const float* __restrict__ pc, const float* __restrict__ cc,
    int* __restrict__ idx, float* __restrict__ wts) {
  __shared__ __align__(16) float4 ctr[M_];     // 32 KB
  __shared__ double mk[8][3][128];             // 24 KB
  int b = blockIdx.y;
  int t = threadIdx.x;
  const float* ccb = cc + (size_t)b * 3 * M_;
  for (int i = t; i < M_; i += 512) {
    float x = ccb[i], y = ccb[M_ + i], z = ccb[2 * M_ + i];
    ctr[i] = make_float4(x, y, z, x * x + y * y + z * z);
  }
  __syncthreads();
  int wv = t >> 6, lane = t & 63;
  int base = blockIdx.x * 128;
  const float* pcb = pc + (size_t)b * 3 * N_;
  int na = base + lane, nb = base + 64 + lane;
  float pxa = pcb[na], pya = pcb[N_ + na], pza = pcb[2 * N_ + na];
  float pxb = pcb[nb], pyb = pcb[N_ + nb], pzb = pcb[2 * N_ + nb];
  float p2a = pxa * pxa + pya * pya + pza * pza;
  float p2b = pxb * pxb + pyb * pyb + pzb * pzb;
  const double kinit = __hiloint2double(0x7F7FFFFF, 0);
  double a0 = kinit, a1 = kinit, a2 = kinit;
  double e0 = kinit, e1 = kinit, e2 = kinit;
  const float4* C = ctr + wv * 256;
  int mbase = wv * 256;
#pragma unroll 8
  for (int m = 0; m < 256; ++m) {
    float4 c = C[m];                           // wave-uniform -> LDS broadcast
    float dota = pxa * c.x;
    dota = __builtin_fmaf(pya, c.y, dota);
    dota = __builtin_fmaf(pza, c.z, dota);
    float da = __builtin_fmaf(-2.f, dota, c.w) + p2a;
    float dotb = pxb * c.x;
    dotb = __builtin_fmaf(pyb, c.y, dotb);
    dotb = __builtin_fmaf(pzb, c.z, dotb);
    float db = __builtin_fmaf(-2.f, dotb, c.w) + p2b;
    double ka = __hiloint2double(__float_as_int(da), mbase + m);
    double kb = __hiloint2double(__float_as_int(db), mbase + m);
    double t0 = fmin(ka, a0);
    double t1 = fmin(fmax(ka, a0), a1);
    double t2 = fmin(fmax(ka, a1), a2);
    a0 = t0; a1 = t1; a2 = t2;
    double u0 = fmin(kb, e0);
    double u1 = fmin(fmax(kb, e0), e1);
    double u2 = fmin(fmax(kb, e1), e2);
    e0 = u0; e1 = u1; e2 = u2;
  }
  mk[wv][0][lane] = a0; mk[wv][1][lane] = a1; mk[wv][2][lane] = a2;
  mk[wv][0][64 + lane] = e0; mk[wv][1][64 + lane] = e1; mk[wv][2][64 + lane] = e2;
  __syncthreads();
  if (t < 128) {
    double k0 = kinit, k1 = kinit, k2 = kinit;
#pragma unroll
    for (int w = 0; w < 8; ++w) {
#pragma unroll
      for (int j = 0; j < 3; ++j) {
        double key = mk[w][j][t];
        double n0 = fmin(key, k0);
        double n1 = fmin(fmax(key, k0), k1);
        double n2 = fmin(fmax(key, k1), k2);
        k0 = n0; k1 = n1; k2 = n2;
      }
    }
    float d0 = __int_as_float(__double2hiint(k0));
    float d1 = __int_as_float(__double2hiint(k1));
    float d2 = __int_as_float(__double2hiint(k2));
    float w0 = 1.f / (d0 + 1e-8f), w1 = 1.f / (d1 + 1e-8f), w2 = 1.f / (d2 + 1e-8f);
    float inv = 1.f / (w0 + w1 + w2);
    int bn = b * N_ + base + t;
    wts[bn] = w0 * inv; wts[B_ * N_ + bn] = w1 * inv; wts[2 * B_ * N_ + bn] = w2 * inv;
    idx[bn] = __double2loint(k0);
    idx[B_ * N_ + bn] = __double2loint(k1);
    idx[2 * B_ * N_ + bn] = __double2loint(k2);
  }
}

// ---------------- gather + weighted sum -> x0T[b][n][0..256) ----------------
__global__ __launch_bounds__(256) void k_interp(
    const short* __restrict__ FT, const int* __restrict__ idx,
    const float* __restrict__ wts, short* __restrict__ x0T) {
  int b = blockIdx.y;
  int t = threadIdx.x;
  int nl = t >> 5, cch = (t & 31) * 8;
  int n = blockIdx.x * 8 + nl;
  int bn = b * N_ + n;
  int i0 = idx[bn], i1 = idx[B_ * N_ + bn], i2 = idx[2 * B_ * N_ + bn];
  float w0 = wts[bn], w1 = wts[B_ * N_ + bn], w2 = wts[2 * B_ * N_ + bn];
  const short* Fb = FT + (size_t)b * M_ * CC_;
  short8 f0 = *(const short8*)(Fb + (size_t)i0 * CC_ + cch);
  short8 f1 = *(const short8*)(Fb + (size_t)i1 * CC_ + cch);
  short8 f2 = *(const short8*)(Fb + (size_t)i2 * CC_ + cch);
  short8 r;
#pragma unroll
  for (int e = 0; e < 8; ++e) {
    float v = w0 * bf2f((unsigned short)f0[e]) + w1 * bf2f((unsigned short)f1[e]) +
              w2 * bf2f((unsigned short)f2[e]);
    r[e] = (short)f2bf(v);
  }
  *(short8*)(x0T + (size_t)bn * CIN_ + cch) = r;
}

// ---------------- bf16 MFMA GEMM + fused GN partial stats ----------------
// part layout: [b*8+grp][64 ntiles][2]
__global__ __launch_bounds__(256) void k_gemm(
    const short* __restrict__ Wb, const short* __restrict__ Xb,
    const float* __restrict__ bias, short* __restrict__ Yb,
    float* __restrict__ part, int K) {
  __shared__ __align__(16) short sW[128 * 64];   // 16 KB
  __shared__ __align__(16) short sX[128 * 64];   // 16 KB
  int b = blockIdx.z;
  int otile = blockIdx.x * 128;
  int ntile = blockIdx.y * 128;
  int t = threadIdx.x;
  int wv = t >> 6, lane = t & 63;
  int wr = wv >> 1, wc = wv & 1;
  int fr = lane & 15;     // fragment row
  int g = lane >> 4;      // k-subchunk selector
  f32x4 acc[4][4] = {};
  const short* Wp = Wb + (size_t)otile * K;
  const short* Xp = Xb + ((size_t)b * N_ + ntile) * K;
  for (int k0 = 0; k0 < K; k0 += 64) {
#pragma unroll
    for (int j = 0; j < 4; ++j) {
      int s = j * 256 + t;          // slot 0..1023, 16B each
      int row = s >> 3;             // 8 slots (128B) per row
      int kc = (s & 7) ^ (row & 7); // inverse-swizzled source chunk
      gload16(Wp + (size_t)row * K + k0 + kc * 8, sW + j * 2048 + wv * 512);
      gload16(Xp + (size_t)row * K + k0 + kc * 8, sX + j * 2048 + wv * 512);
    }
    __syncthreads();
#pragma unroll
    for (int h = 0; h < 2; ++h) {
      short8 af[4], bfr[4];
#pragma unroll
      for (int m = 0; m < 4; ++m) {
        int ra = wr * 64 + m * 16 + fr;
        af[m] = *(const short8*)(sW + ra * 64 + (((h * 4 + g) ^ (ra & 7)) << 3));
        int rb = wc * 64 + m * 16 + fr;
        bfr[m] = *(const short8*)(sX + rb * 64 + (((h * 4 + g) ^ (rb & 7)) << 3));
      }
#pragma unroll
      for (int m = 0; m < 4; ++m)
#pragma unroll
        for (int nn = 0; nn < 4; ++nn)
          acc[m][nn] = __builtin_amdgcn_mfma_f32_16x16x32_bf16(af[m], bfr[nn], acc[m][nn], 0, 0, 0);
    }
    __syncthreads();
  }
  // epilogue: store + per-lane GN partials (m<2 -> local group wr*2, m>=2 -> wr*2+1)
  float s01 = 0.f, ss01 = 0.f, s23 = 0.f, ss23 = 0.f;
#pragma unroll
  for (int m = 0; m < 4; ++m) {
    int o = otile + wr * 64 + m * 16 + g * 4;
    float4 bi = *(const float4*)(bias + o);
#pragma unroll
    for (int nn = 0; nn < 4; ++nn) {
      int n = ntile + wc * 64 + nn * 16 + fr;
      float v0 = acc[m][nn][0] + bi.x;
      float v1 = acc[m][nn][1] + bi.y;
      float v2 = acc[m][nn][2] + bi.z;
      float v3 = acc[m][nn][3] + bi.w;
      if (m < 2) { s01 += v0 + v1 + v2 + v3; ss01 += v0*v0 + v1*v1 + v2*v2 + v3*v3; }
      else       { s23 += v0 + v1 + v2 + v3; ss23 += v0*v0 + v1*v1 + v2*v2 + v3*v3; }
      short4v sv;
      sv[0] = (short)f2bf(v0);
      sv[1] = (short)f2bf(v1);
      sv[2] = (short)f2bf(v2);
      sv[3] = (short)f2bf(v3);
      *(short4v*)(Yb + ((size_t)b * N_ + n) * 256 + o) = sv;
    }
  }
#pragma unroll
  for (int off = 32; off > 0; off >>= 1) {
    s01 += __shfl_down(s01, off);
    ss01 += __shfl_down(ss01, off);
    s23 += __shfl_down(s23, off);
    ss23 += __shfl_down(ss23, off);
  }
  float* wred = (float*)sW;   // LDS reuse (k-loop done, post-barrier)
  if (lane == 0) {
    wred[wv * 4 + 0] = s01; wred[wv * 4 + 1] = ss01;
    wred[wv * 4 + 2] = s23; wred[wv * 4 + 3] = ss23;
  }
  __syncthreads();
  if (t < 8) {
    int gl = t >> 1, sel = t & 1;                 // local group 0..3, sum/sumsq
    int wrn = gl >> 1;                            // which wr produced it
    int id = (gl & 1) * 2 + sel;                  // s01/ss01 vs s23/ss23
    float v = wred[(wrn * 2 + 0) * 4 + id] + wred[(wrn * 2 + 1) * 4 + id];
    part[(((size_t)b * 8 + blockIdx.x * 4 + gl) * 64 + blockIdx.y) * 2 + sel] = v;
  }
}

// ---------------- GN + swish in place (bf16 [b][n][256]), stats finalized in-block ----
__global__ __launch_bounds__(256) void k_gnapply(short* __restrict__ Y,
                                                 const float* __restrict__ part,
                                                 const float* __restrict__ gw,
                                                 const float* __restrict__ gb) {
  __shared__ float fs[128];
  int t = threadIdx.x;
  if (t < 64) {
    float s = 0.f, ss = 0.f;
    for (int j = 0; j < 64; ++j) {
      s += part[((size_t)t * 64 + j) * 2];
      ss += part[((size_t)t * 64 + j) * 2 + 1];
    }
    const float cnt = 32.f * 8192.f;
    float mean = s / cnt;
    float var = ss / cnt - mean * mean;
    fs[t * 2] = mean;
    fs[t * 2 + 1] = rsqrtf(var + 1e-5f);
  }
  __syncthreads();
  unsigned int* Yd = (unsigned int*)Y;
  int total = B_ * N_ * 128;
  for (int i = blockIdx.x * blockDim.x + t; i < total;
       i += gridDim.x * blockDim.x) {
    int o2 = i & 127;
    int b = i >> 20;
    int g = o2 >> 4;
    float mean = fs[(b * 8 + g) * 2], rstd = fs[(b * 8 + g) * 2 + 1];
    unsigned int v = Yd[i];
    int o = o2 * 2;
    float a = bf2f((unsigned short)(v & 0xFFFF));
    float c = bf2f((unsigned short)(v >> 16));
    a = (a - mean) * rstd * gw[o] + gb[o];
    c = (c - mean) * rstd * gw[o + 1] + gb[o + 1];
    a = a / (1.f + __expf(-a));
    c = c / (1.f + __expf(-c));
    Yd[i] = (unsigned int)f2bf(a) | ((unsigned int)f2bf(c) << 16);
  }
}

// ---------------- GN + swish + transpose -> out [b][o][n] f32, stats in-block ----------
__global__ __launch_bounds__(256) void k_gnapply_out(
    const short* __restrict__ Y, const float* __restrict__ part,
    const float* __restrict__ gw, const float* __restrict__ gb,
    float* __restrict__ out) {
  __shared__ float tile[64][65];
  __shared__ float fs[16];
  int b = blockIdx.z;
  int t = threadIdx.x;
  if (t < 8) {
    float s = 0.f, ss = 0.f;
    for (int j = 0; j < 64; ++j) {
      s += part[(((size_t)b * 8 + t) * 64 + j) * 2];
      ss += part[(((size_t)b * 8 + t) * 64 + j) * 2 + 1];
    }
    const float cnt = 32.f * 8192.f;
    float mean = s / cnt;
    float var = ss / cnt - mean * mean;
    fs[t * 2] = mean;
    fs[t * 2 + 1] = rsqrtf(var + 1e-5f);
  }
  __syncthreads();
  int n0 = blockIdx.x * 64, o0 = blockIdx.y * 64;
  int row = t >> 5, dcol = t & 31;
  const unsigned int* Yd = (const unsigned int*)(Y + (size_t)b * N_ * 256);
  int o = o0 + dcol * 2;
  int g = o >> 5;
  float mean = fs[g * 2], rstd = fs[g * 2 + 1];
  float w0 = gw[o], w1 = gw[o + 1], bb0 = gb[o], bb1 = gb[o + 1];
#pragma unroll
  for (int p = 0; p < 8; ++p) {
    int n = n0 + p * 8 + row;
    unsigned int v = Yd[(size_t)n * 128 + (o0 >> 1) + dcol];
    float a = bf2f((unsigned short)(v & 0xFFFF));
    float c = bf2f((unsigned short)(v >> 16));
    a = (a - mean) * rstd * w0 + bb0; a = a / (1.f + __expf(-a));
    c = (c - mean) * rstd * w1 + bb1; c = c / (1.f + __expf(-c));
    tile[p * 8 + row][dcol * 2] = a;
    tile[p * 8 + row][dcol * 2 + 1] = c;
  }
  __syncthreads();
  int ol = t >> 2, nch = (t & 3) * 16;
  float* ob = out + ((size_t)(b * 256 + o0 + ol)) * N_ + n0 + nch;
#pragma unroll
  for (int c4 = 0; c4 < 16; c4 += 4) {
    float4 v4;
    v4.x = tile[nch + c4 + 0][ol];
    v4.y = tile[nch + c4 + 1][ol];
    v4.z = tile[nch + c4 + 2][ol];
    v4.w = tile[nch + c4 + 3][ol];
    *(float4*)(ob + c4) = v4;
  }
}

// ---------------- tail: coords copy + time_emb broadcast ----------------
__global__ void k_tail(const float* __restrict__ pc, const float* __restrict__ te,
                       float* __restrict__ out) {
  int total = 196608 + B_ * 64 * N_;
  for (int i = blockIdx.x * blockDim.x + threadIdx.x; i < total;
       i += gridDim.x * blockDim.x) {
    if (i < 196608) {
      out[16777216 + i] = pc[i];
    } else {
      int j = i - 196608;
      int bd = j >> 13;
      out[16973824 + j] = te[bd];
    }
  }
}

extern "C" void kernel_launch(void* const* d_in, const int* in_sizes, int n_in,
                              void* d_out, int out_size, void* d_ws, size_t ws_size,
                              hipStream_t stream) {
  const float* pc  = (const float*)d_in[0];
  const float* cc  = (const float*)d_in[1];
  const float* cf  = (const float*)d_in[2];
  const float* pf  = (const float*)d_in[3];
  const float* te  = (const float*)d_in[4];
  const float* W1  = (const float*)d_in[5];
  const float* b1  = (const float*)d_in[6];
  const float* g1w = (const float*)d_in[7];
  const float* g1b = (const float*)d_in[8];
  const float* W2  = (const float*)d_in[9];
  const float* b2  = (const float*)d_in[10];
  const float* g2w = (const float*)d_in[11];
  const float* g2b = (const float*)d_in[12];
  float* out = (float*)d_out;

  char* ws = (char*)d_ws;
  size_t off = 0;
  auto alloc = [&](size_t bytes) {
    char* p = ws + off;
    off += (bytes + 255) & ~(size_t)255;
    return p;
  };
  short* FT   = (short*)alloc((size_t)B_ * M_ * CC_ * 2);       // 8.4 MB
  short* x0T  = (short*)alloc((size_t)B_ * N_ * CIN_ * 2);      // 50.3 MB
  short* y1   = (short*)alloc((size_t)B_ * N_ * 256 * 2);       // 33.6 MB
  short* W1b  = (short*)alloc(256 * 384 * 2);
  short* W2b  = (short*)alloc(256 * 256 * 2);
  int*   idx  = (int*)alloc((size_t)3 * B_ * N_ * 4);
  float* wts  = (float*)alloc((size_t)3 * B_ * N_ * 4);
  float* part1 = (float*)alloc(8 * 8 * 64 * 2 * 4);
  float* part2 = (float*)alloc(8 * 8 * 64 * 2 * 4);
  short* y2 = (short*)x0T;  // x0T dead after gemm1; reuse for y2

  k_prep<<<12672, 256, 0, stream>>>(W1, W2, W1b, W2b, cf, FT, pf, x0T);
  k_knn<<<dim3(N_ / 128, B_), 512, 0, stream>>>(pc, cc, idx, wts);
  k_interp<<<dim3(N_ / 8, B_), 256, 0, stream>>>(FT, idx, wts, x0T);
  k_gemm<<<dim3(2, N_ / 128, B_), 256, 0, stream>>>(W1b, x0T, b1, y1, part1, CIN_);
  k_gnapply<<<2048, 256, 0, stream>>>(y1, part1, g1w, g1b);
  k_gemm<<<dim3(2, N_ / 128, B_), 256, 0, stream>>>(W2b, y1, b2, y2, part2, 256);
  k_gnapply_out<<<dim3(N_ / 64, 4, B_), 256, 0, stream>>>(y2, part2, g2w, g2b, out);
  k_tail<<<2048, 256, 0, stream>>>(pc, te, out);
}

// Round 7
// 191.204 us; speedup vs baseline: 2.1308x; 1.0190x over previous
//
#include <hip/hip_runtime.h>
#include <hip/hip_bf16.h>
#include <float.h>

#define B_ 8
#define N_ 8192
#define M_ 2048
#define CC_ 256
#define CP_ 128
#define CIN_ 384
#define GRP_ 8

typedef __attribute__((ext_vector_type(8))) short short8;
typedef __attribute__((ext_vector_type(4))) short short4v;
typedef __attribute__((ext_vector_type(4))) float f32x4;

static __device__ __forceinline__ float bf2f(unsigned short u) {
  union { unsigned int i; float f; } v; v.i = ((unsigned int)u) << 16; return v.f;
}
static __device__ __forceinline__ unsigned short f2bf(float f) {
  union { float f; unsigned int i; } v; v.f = f;
  unsigned int u = v.i;
  unsigned int r = (u + 0x7FFFu + ((u >> 16) & 1u)) >> 16;
  return (unsigned short)r;
}
static __device__ __forceinline__ void gload16(const void* g, void* l) {
  __builtin_amdgcn_global_load_lds(
      (const __attribute__((address_space(1))) void*)g,
      (__attribute__((address_space(3))) void*)l, 16, 0, 0);
}

// ---------------- fused front: knn + wcast + transpose-casts + tail ----------------
// blocks [0,512): knn | [512,704): wcast | [704,6848): transpose tiles (2/blk) | [6848,7360): tail
__global__ __launch_bounds__(512) void k_front(
    const float* __restrict__ pc, const float* __restrict__ cc,
    int* __restrict__ idx, float* __restrict__ wts,
    const float* __restrict__ W1, const float* __restrict__ W2,
    short* __restrict__ W1b, short* __restrict__ W2b,
    const float* __restrict__ cf, short* __restrict__ FT,
    const float* __restrict__ pf, short* __restrict__ x0T,
    const float* __restrict__ te, float* __restrict__ out) {
  __shared__ __align__(16) char smem[57344];
  int bid = blockIdx.x;
  int t = threadIdx.x;
  if (bid < 512) {
    // ---- 3-NN: 8 waves, 8-way M-chunks, 2 pts/thread, f64 packed keys (exact) ----
    float4* ctr = (float4*)smem;                          // 32 KB
    double (*mk)[3][128] = (double(*)[3][128])(smem + 32768);  // 24 KB
    int b = bid >> 6;
    int base = (bid & 63) * 128;
    const float* ccb = cc + (size_t)b * 3 * M_;
    for (int i = t; i < M_; i += 512) {
      float x = ccb[i], y = ccb[M_ + i], z = ccb[2 * M_ + i];
      ctr[i] = make_float4(x, y, z, x * x + y * y + z * z);
    }
    __syncthreads();
    int wv = t >> 6, lane = t & 63;
    const float* pcb = pc + (size_t)b * 3 * N_;
    int na = base + lane, nb = base + 64 + lane;
    float pxa = pcb[na], pya = pcb[N_ + na], pza = pcb[2 * N_ + na];
    float pxb = pcb[nb], pyb = pcb[N_ + nb], pzb = pcb[2 * N_ + nb];
    float p2a = pxa * pxa + pya * pya + pza * pza;
    float p2b = pxb * pxb + pyb * pyb + pzb * pzb;
    const double kinit = __hiloint2double(0x7F7FFFFF, 0);
    double a0 = kinit, a1 = kinit, a2 = kinit;
    double e0 = kinit, e1 = kinit, e2 = kinit;
    const float4* C = ctr + wv * 256;
    int mbase = wv * 256;
#pragma unroll 8
    for (int m = 0; m < 256; ++m) {
      float4 c = C[m];                           // wave-uniform -> LDS broadcast
      float dota = pxa * c.x;
      dota = __builtin_fmaf(pya, c.y, dota);
      dota = __builtin_fmaf(pza, c.z, dota);
      float da = __builtin_fmaf(-2.f, dota, c.w) + p2a;
      float dotb = pxb * c.x;
      dotb = __builtin_fmaf(pyb, c.y, dotb);
      dotb = __builtin_fmaf(pzb, c.z, dotb);
      float db = __builtin_fmaf(-2.f, dotb, c.w) + p2b;
      double ka = __hiloint2double(__float_as_int(da), mbase + m);
      double kb = __hiloint2double(__float_as_int(db), mbase + m);
      double t0 = fmin(ka, a0);
      double t1 = fmin(fmax(ka, a0), a1);
      double t2 = fmin(fmax(ka, a1), a2);
      a0 = t0; a1 = t1; a2 = t2;
      double u0 = fmin(kb, e0);
      double u1 = fmin(fmax(kb, e0), e1);
      double u2 = fmin(fmax(kb, e1), e2);
      e0 = u0; e1 = u1; e2 = u2;
    }
    mk[wv][0][lane] = a0; mk[wv][1][lane] = a1; mk[wv][2][lane] = a2;
    mk[wv][0][64 + lane] = e0; mk[wv][1][64 + lane] = e1; mk[wv][2][64 + lane] = e2;
    __syncthreads();
    if (t < 128) {
      double k0 = kinit, k1 = kinit, k2 = kinit;
#pragma unroll
      for (int w = 0; w < 8; ++w) {
#pragma unroll
        for (int j = 0; j < 3; ++j) {
          double key = mk[w][j][t];
          double n0 = fmin(key, k0);
          double n1 = fmin(fmax(key, k0), k1);
          double n2 = fmin(fmax(key, k1), k2);
          k0 = n0; k1 = n1; k2 = n2;
        }
      }
      float d0 = __int_as_float(__double2hiint(k0));
      float d1 = __int_as_float(__double2hiint(k1));
      float d2 = __int_as_float(__double2hiint(k2));
      float w0 = 1.f / (d0 + 1e-8f), w1 = 1.f / (d1 + 1e-8f), w2 = 1.f / (d2 + 1e-8f);
      float inv = 1.f / (w0 + w1 + w2);
      int bn = b * N_ + base + t;
      wts[bn] = w0 * inv; wts[B_ * N_ + bn] = w1 * inv; wts[2 * B_ * N_ + bn] = w2 * inv;
      idx[bn] = __double2loint(k0);
      idx[B_ * N_ + bn] = __double2loint(k1);
      idx[2 * B_ * N_ + bn] = __double2loint(k2);
    }
  } else if (bid < 704) {
    // ---- weight cast ----
    int i = (bid - 512) * 512 + t;
    if (i < 256 * CIN_) W1b[i] = (short)f2bf(W1[i]);
    if (i < 256 * 256)  W2b[i] = (short)f2bf(W2[i]);
  } else if (bid < 6848) {
    // ---- transpose+cast, two 32x32 tiles per block ----
    int q2 = (bid - 704) * 2 + (t >> 8);
    int tt = t & 255;
    float (*tile)[33] = (float(*)[33])(smem + (t >> 8) * 4352);
    const float* in; short* outp;
    int C, Nn, RS, coff, n0, c0, b;
    if (q2 < 4096) {
      in = cf; outp = FT; C = CC_; Nn = M_; RS = CC_; coff = 0;
      n0 = (q2 & 63) * 32; c0 = ((q2 >> 6) & 7) * 32; b = q2 >> 9;
    } else {
      int q = q2 - 4096;
      in = pf; outp = x0T; C = CP_; Nn = N_; RS = CIN_; coff = 256;
      n0 = (q & 255) * 32; c0 = ((q >> 8) & 3) * 32; b = q >> 10;
    }
    const float* inb = in + (size_t)b * C * Nn;
    short* outb = outp + (size_t)b * Nn * RS;
    int tx = tt & 31, ty = tt >> 5;
#pragma unroll
    for (int i = 0; i < 32; i += 8)
      tile[ty + i][tx] = inb[(size_t)(c0 + ty + i) * Nn + n0 + tx];
    __syncthreads();
#pragma unroll
    for (int i = 0; i < 32; i += 8)
      outb[(size_t)(n0 + ty + i) * RS + coff + c0 + tx] = (short)f2bf(tile[tx][ty + i]);
  } else {
    // ---- tail: coords copy + time_emb broadcast ----
    int total = 196608 + B_ * 64 * N_;
    for (int i = (bid - 6848) * 512 + t; i < total; i += 512 * 512) {
      if (i < 196608) {
        out[16777216 + i] = pc[i];
      } else {
        int j = i - 196608;
        int bd = j >> 13;
        out[16973824 + j] = te[bd];
      }
    }
  }
}

// ---------------- gather + weighted sum -> x0T[b][n][0..256) ----------------
__global__ __launch_bounds__(256) void k_interp(
    const short* __restrict__ FT, const int* __restrict__ idx,
    const float* __restrict__ wts, short* __restrict__ x0T) {
  int b = blockIdx.y;
  int t = threadIdx.x;
  int nl = t >> 5, cch = (t & 31) * 8;
  int n = blockIdx.x * 8 + nl;
  int bn = b * N_ + n;
  int i0 = idx[bn], i1 = idx[B_ * N_ + bn], i2 = idx[2 * B_ * N_ + bn];
  float w0 = wts[bn], w1 = wts[B_ * N_ + bn], w2 = wts[2 * B_ * N_ + bn];
  const short* Fb = FT + (size_t)b * M_ * CC_;
  short8 f0 = *(const short8*)(Fb + (size_t)i0 * CC_ + cch);
  short8 f1 = *(const short8*)(Fb + (size_t)i1 * CC_ + cch);
  short8 f2 = *(const short8*)(Fb + (size_t)i2 * CC_ + cch);
  short8 r;
#pragma unroll
  for (int e = 0; e < 8; ++e) {
    float v = w0 * bf2f((unsigned short)f0[e]) + w1 * bf2f((unsigned short)f1[e]) +
              w2 * bf2f((unsigned short)f2[e]);
    r[e] = (short)f2bf(v);
  }
  *(short8*)(x0T + (size_t)bn * CIN_ + cch) = r;
}

// ---------------- bf16 MFMA GEMM + fused GN partial stats ----------------
// part layout: [b*8+grp][64 ntiles][2]
__global__ __launch_bounds__(256) void k_gemm(
    const short* __restrict__ Wb, const short* __restrict__ Xb,
    const float* __restrict__ bias, short* __restrict__ Yb,
    float* __restrict__ part, int K) {
  __shared__ __align__(16) short sW[128 * 64];   // 16 KB
  __shared__ __align__(16) short sX[128 * 64];   // 16 KB
  int b = blockIdx.z;
  int otile = blockIdx.x * 128;
  int ntile = blockIdx.y * 128;
  int t = threadIdx.x;
  int wv = t >> 6, lane = t & 63;
  int wr = wv >> 1, wc = wv & 1;
  int fr = lane & 15;     // fragment row
  int g = lane >> 4;      // k-subchunk selector
  f32x4 acc[4][4] = {};
  const short* Wp = Wb + (size_t)otile * K;
  const short* Xp = Xb + ((size_t)b * N_ + ntile) * K;
  for (int k0 = 0; k0 < K; k0 += 64) {
#pragma unroll
    for (int j = 0; j < 4; ++j) {
      int s = j * 256 + t;          // slot 0..1023, 16B each
      int row = s >> 3;             // 8 slots (128B) per row
      int kc = (s & 7) ^ (row & 7); // inverse-swizzled source chunk
      gload16(Wp + (size_t)row * K + k0 + kc * 8, sW + j * 2048 + wv * 512);
      gload16(Xp + (size_t)row * K + k0 + kc * 8, sX + j * 2048 + wv * 512);
    }
    __syncthreads();
#pragma unroll
    for (int h = 0; h < 2; ++h) {
      short8 af[4], bfr[4];
#pragma unroll
      for (int m = 0; m < 4; ++m) {
        int ra = wr * 64 + m * 16 + fr;
        af[m] = *(const short8*)(sW + ra * 64 + (((h * 4 + g) ^ (ra & 7)) << 3));
        int rb = wc * 64 + m * 16 + fr;
        bfr[m] = *(const short8*)(sX + rb * 64 + (((h * 4 + g) ^ (rb & 7)) << 3));
      }
#pragma unroll
      for (int m = 0; m < 4; ++m)
#pragma unroll
        for (int nn = 0; nn < 4; ++nn)
          acc[m][nn] = __builtin_amdgcn_mfma_f32_16x16x32_bf16(af[m], bfr[nn], acc[m][nn], 0, 0, 0);
    }
    __syncthreads();
  }
  // epilogue: store + per-lane GN partials (m<2 -> local group wr*2, m>=2 -> wr*2+1)
  float s01 = 0.f, ss01 = 0.f, s23 = 0.f, ss23 = 0.f;
#pragma unroll
  for (int m = 0; m < 4; ++m) {
    int o = otile + wr * 64 + m * 16 + g * 4;
    float4 bi = *(const float4*)(bias + o);
#pragma unroll
    for (int nn = 0; nn < 4; ++nn) {
      int n = ntile + wc * 64 + nn * 16 + fr;
      float v0 = acc[m][nn][0] + bi.x;
      float v1 = acc[m][nn][1] + bi.y;
      float v2 = acc[m][nn][2] + bi.z;
      float v3 = acc[m][nn][3] + bi.w;
      if (m < 2) { s01 += v0 + v1 + v2 + v3; ss01 += v0*v0 + v1*v1 + v2*v2 + v3*v3; }
      else       { s23 += v0 + v1 + v2 + v3; ss23 += v0*v0 + v1*v1 + v2*v2 + v3*v3; }
      short4v sv;
      sv[0] = (short)f2bf(v0);
      sv[1] = (short)f2bf(v1);
      sv[2] = (short)f2bf(v2);
      sv[3] = (short)f2bf(v3);
      *(short4v*)(Yb + ((size_t)b * N_ + n) * 256 + o) = sv;
    }
  }
#pragma unroll
  for (int off = 32; off > 0; off >>= 1) {
    s01 += __shfl_down(s01, off);
    ss01 += __shfl_down(ss01, off);
    s23 += __shfl_down(s23, off);
    ss23 += __shfl_down(ss23, off);
  }
  float* wred = (float*)sW;   // LDS reuse (k-loop done, post-barrier)
  if (lane == 0) {
    wred[wv * 4 + 0] = s01; wred[wv * 4 + 1] = ss01;
    wred[wv * 4 + 2] = s23; wred[wv * 4 + 3] = ss23;
  }
  __syncthreads();
  if (t < 8) {
    int gl = t >> 1, sel = t & 1;                 // local group 0..3, sum/sumsq
    int wrn = gl >> 1;                            // which wr produced it
    int id = (gl & 1) * 2 + sel;                  // s01/ss01 vs s23/ss23
    float v = wred[(wrn * 2 + 0) * 4 + id] + wred[(wrn * 2 + 1) * 4 + id];
    part[(((size_t)b * 8 + blockIdx.x * 4 + gl) * 64 + blockIdx.y) * 2 + sel] = v;
  }
}

// ---------------- GN + swish in place (bf16 [b][n][256]), stats finalized in-block ----
__global__ __launch_bounds__(256) void k_gnapply(short* __restrict__ Y,
                                                 const float* __restrict__ part,
                                                 const float* __restrict__ gw,
                                                 const float* __restrict__ gb) {
  __shared__ float fs[128];
  int t = threadIdx.x;
  if (t < 64) {
    float s = 0.f, ss = 0.f;
    for (int j = 0; j < 64; ++j) {
      s += part[((size_t)t * 64 + j) * 2];
      ss += part[((size_t)t * 64 + j) * 2 + 1];
    }
    const float cnt = 32.f * 8192.f;
    float mean = s / cnt;
    float var = ss / cnt - mean * mean;
    fs[t * 2] = mean;
    fs[t * 2 + 1] = rsqrtf(var + 1e-5f);
  }
  __syncthreads();
  unsigned int* Yd = (unsigned int*)Y;
  int total = B_ * N_ * 128;
  for (int i = blockIdx.x * blockDim.x + t; i < total;
       i += gridDim.x * blockDim.x) {
    int o2 = i & 127;
    int b = i >> 20;
    int g = o2 >> 4;
    float mean = fs[(b * 8 + g) * 2], rstd = fs[(b * 8 + g) * 2 + 1];
    unsigned int v = Yd[i];
    int o = o2 * 2;
    float a = bf2f((unsigned short)(v & 0xFFFF));
    float c = bf2f((unsigned short)(v >> 16));
    a = (a - mean) * rstd * gw[o] + gb[o];
    c = (c - mean) * rstd * gw[o + 1] + gb[o + 1];
    a = a / (1.f + __expf(-a));
    c = c / (1.f + __expf(-c));
    Yd[i] = (unsigned int)f2bf(a) | ((unsigned int)f2bf(c) << 16);
  }
}

// ---------------- GN + swish + transpose -> out [b][o][n] f32, stats in-block ----------
__global__ __launch_bounds__(256) void k_gnapply_out(
    const short* __restrict__ Y, const float* __restrict__ part,
    const float* __restrict__ gw, const float* __restrict__ gb,
    float* __restrict__ out) {
  __shared__ float tile[64][65];
  __shared__ float fs[16];
  int b = blockIdx.z;
  int t = threadIdx.x;
  if (t < 8) {
    float s = 0.f, ss = 0.f;
    for (int j = 0; j < 64; ++j) {
      s += part[(((size_t)b * 8 + t) * 64 + j) * 2];
      ss += part[(((size_t)b * 8 + t) * 64 + j) * 2 + 1];
    }
    const float cnt = 32.f * 8192.f;
    float mean = s / cnt;
    float var = ss / cnt - mean * mean;
    fs[t * 2] = mean;
    fs[t * 2 + 1] = rsqrtf(var + 1e-5f);
  }
  __syncthreads();
  int n0 = blockIdx.x * 64, o0 = blockIdx.y * 64;
  int row = t >> 5, dcol = t & 31;
  const unsigned int* Yd = (const unsigned int*)(Y + (size_t)b * N_ * 256);
  int o = o0 + dcol * 2;
  int g = o >> 5;
  float mean = fs[g * 2], rstd = fs[g * 2 + 1];
  float w0 = gw[o], w1 = gw[o + 1], bb0 = gb[o], bb1 = gb[o + 1];
#pragma unroll
  for (int p = 0; p < 8; ++p) {
    int n = n0 + p * 8 + row;
    unsigned int v = Yd[(size_t)n * 128 + (o0 >> 1) + dcol];
    float a = bf2f((unsigned short)(v & 0xFFFF));
    float c = bf2f((unsigned short)(v >> 16));
    a = (a - mean) * rstd * w0 + bb0; a = a / (1.f + __expf(-a));
    c = (c - mean) * rstd * w1 + bb1; c = c / (1.f + __expf(-c));
    tile[p * 8 + row][dcol * 2] = a;
    tile[p * 8 + row][dcol * 2 + 1] = c;
  }
  __syncthreads();
  int ol = t >> 2, nch = (t & 3) * 16;
  float* ob = out + ((size_t)(b * 256 + o0 + ol)) * N_ + n0 + nch;
#pragma unroll
  for (int c4 = 0; c4 < 16; c4 += 4) {
    float4 v4;
    v4.x = tile[nch + c4 + 0][ol];
    v4.y = tile[nch + c4 + 1][ol];
    v4.z = tile[nch + c4 + 2][ol];
    v4.w = tile[nch + c4 + 3][ol];
    *(float4*)(ob + c4) = v4;
  }
}

extern "C" void kernel_launch(void* const* d_in, const int* in_sizes, int n_in,
                              void* d_out, int out_size, void* d_ws, size_t ws_size,
                              hipStream_t stream) {
  const float* pc  = (const float*)d_in[0];
  const float* cc  = (const float*)d_in[1];
  const float* cf  = (const float*)d_in[2];
  const float* pf  = (const float*)d_in[3];
  const float* te  = (const float*)d_in[4];
  const float* W1  = (const float*)d_in[5];
  const float* b1  = (const float*)d_in[6];
  const float* g1w = (const float*)d_in[7];
  const float* g1b = (const float*)d_in[8];
  const float* W2  = (const float*)d_in[9];
  const float* b2  = (const float*)d_in[10];
  const float* g2w = (const float*)d_in[11];
  const float* g2b = (const float*)d_in[12];
  float* out = (float*)d_out;

  char* ws = (char*)d_ws;
  size_t off = 0;
  auto alloc = [&](size_t bytes) {
    char* p = ws + off;
    off += (bytes + 255) & ~(size_t)255;
    return p;
  };
  short* FT   = (short*)alloc((size_t)B_ * M_ * CC_ * 2);       // 8.4 MB
  short* x0T  = (short*)alloc((size_t)B_ * N_ * CIN_ * 2);      // 50.3 MB
  short* y1   = (short*)alloc((size_t)B_ * N_ * 256 * 2);       // 33.6 MB
  short* W1b  = (short*)alloc(256 * 384 * 2);
  short* W2b  = (short*)alloc(256 * 256 * 2);
  int*   idx  = (int*)alloc((size_t)3 * B_ * N_ * 4);
  float* wts  = (float*)alloc((size_t)3 * B_ * N_ * 4);
  float* part1 = (float*)alloc(8 * 8 * 64 * 2 * 4);
  float* part2 = (float*)alloc(8 * 8 * 64 * 2 * 4);
  short* y2 = (short*)x0T;  // x0T dead after gemm1; reuse for y2

  k_front<<<7360, 512, 0, stream>>>(pc, cc, idx, wts, W1, W2, W1b, W2b,
                                    cf, FT, pf, x0T, te, out);
  k_interp<<<dim3(N_ / 8, B_), 256, 0, stream>>>(FT, idx, wts, x0T);
  k_gemm<<<dim3(2, N_ / 128, B_), 256, 0, stream>>>(W1b, x0T, b1, y1, part1, CIN_);
  k_gnapply<<<2048, 256, 0, stream>>>(y1, part1, g1w, g1b);
  k_gemm<<<dim3(2, N_ / 128, B_), 256, 0, stream>>>(W2b, y1, b2, y2, part2, 256);
  k_gnapply_out<<<dim3(N_ / 64, 4, B_), 256, 0, stream>>>(y2, part2, g2w, g2b, out);
}